// Round 1
// baseline (32786.407 us; speedup 1.0000x reference)
//
#include <hip/hip_runtime.h>
#include <math.h>

#define B 4
#define T 512
#define D 256
#define H 1024
#define NH 8
#define HD 32
#define V 32000
#define BT (B*T)
#define LE 2
#define LD 2

// ---------------------------------------------------------------------------
// embed + rope fused: out [BT, D, 4]
__global__ __launch_bounds__(256) void embed_rope_kernel(
    const int* __restrict__ ids, const float* __restrict__ emb, float* __restrict__ out) {
  int bt = blockIdx.x;
  int d  = threadIdx.x;
  int id = ids[bt];
  int t  = bt % T;
  size_t VD = (size_t)V * D;
  float scale = powf(10000.f, -(float)d / (float)D);
  float r = emb[(size_t)id * D + d];
  float i = emb[VD + (size_t)id * D + d] * scale;
  float j = emb[2 * VD + (size_t)id * D + d] * scale;
  float k = emb[3 * VD + (size_t)id * D + d] * scale;
  float n = sqrtf(r * r + i * i + j * j + k * k + 1e-6f);
  float ang;
  if (d < D / 2) {
    float inv = powf(10000.f, -(float)(2 * d) / (float)D);
    ang = sinf((float)t * inv);
  } else {
    float inv = powf(10000.f, -(float)(2 * (d - D / 2)) / (float)D);
    ang = cosf((float)t * inv);
  }
  float s = ang / n;
  size_t base = ((size_t)bt * D + d) * 4;
  out[base + 0] = r * s;
  out[base + 1] = i * s;
  out[base + 2] = j * s;
  out[base + 3] = k * s;
}

// ---------------------------------------------------------------------------
// quaternion linear: x [BT, Din, 4], W [4, Dout, Din], bias [Dout,4] or null
// out [BT, Dout, 4].  grid (BT, Dout/256), block 256.
__global__ __launch_bounds__(256) void qlinear_kernel(
    const float* __restrict__ x, const float* __restrict__ W,
    const float* __restrict__ bias, float* __restrict__ out, int Din, int Dout) {
  __shared__ float xs[4096];  // up to Din=1024 * 4 comps
  int n = blockIdx.x;
  int o = blockIdx.y * 256 + threadIdx.x;
  int tot = Din * 4;
  for (int idx = threadIdx.x; idx < tot; idx += 256)
    xs[idx] = x[(size_t)n * tot + idx];
  __syncthreads();
  size_t WD = (size_t)Dout * Din;
  const float4* wr4 = (const float4*)(W + (size_t)o * Din);
  const float4* wi4 = (const float4*)(W + WD + (size_t)o * Din);
  const float4* wj4 = (const float4*)(W + 2 * WD + (size_t)o * Din);
  const float4* wk4 = (const float4*)(W + 3 * WD + (size_t)o * Din);
  float ro = 0.f, io = 0.f, jo = 0.f, ko = 0.f;
  int nd4 = Din >> 2;
  for (int d4 = 0; d4 < nd4; ++d4) {
    float4 wr = wr4[d4], wi = wi4[d4], wj = wj4[d4], wk = wk4[d4];
    const float* xp = xs + d4 * 16;
#define QSTEP(u, WR, WI, WJ, WK) {                      \
    float rr = xp[(u)*4+0], ii = xp[(u)*4+1],           \
          jj = xp[(u)*4+2], kk = xp[(u)*4+3];           \
    ro += rr*(WR) - ii*(WI) - jj*(WJ) - kk*(WK);        \
    io += rr*(WI) + ii*(WR) + jj*(WK) - kk*(WJ);        \
    jo += rr*(WJ) - ii*(WK) + jj*(WR) + kk*(WI);        \
    ko += rr*(WK) + ii*(WJ) - jj*(WI) + kk*(WR); }
    QSTEP(0, wr.x, wi.x, wj.x, wk.x)
    QSTEP(1, wr.y, wi.y, wj.y, wk.y)
    QSTEP(2, wr.z, wi.z, wj.z, wk.z)
    QSTEP(3, wr.w, wi.w, wj.w, wk.w)
#undef QSTEP
  }
  float4 bb = bias ? ((const float4*)bias)[o] : make_float4(0.f, 0.f, 0.f, 0.f);
  float4 res;
  res.x = ro + bb.x; res.y = io + bb.y; res.z = jo + bb.z; res.w = ko + bb.w;
  ((float4*)out)[(size_t)n * Dout + o] = res;
}

// ---------------------------------------------------------------------------
// scores + softmax. grid (T, NH, B), block 512 (one thread per key)
__global__ __launch_bounds__(512) void attn_scores_kernel(
    const float* __restrict__ qp, const float* __restrict__ kp,
    const int* __restrict__ mask, float* __restrict__ wout) {
  int q = blockIdx.x, h = blockIdx.y, b = blockIdx.z;
  int k = threadIdx.x;
  __shared__ float qrow[128];
  __shared__ float red[512];
  if (k < 128) qrow[k] = qp[(((size_t)b * T + q) * D + h * HD) * 4 + k];
  __syncthreads();
  const float* kptr = kp + (((size_t)b * T + k) * D + h * HD) * 4;
  float dot = 0.f;
#pragma unroll
  for (int i = 0; i < 128; i += 4) {
    float4 kv = *(const float4*)(kptr + i);
    dot += qrow[i] * kv.x + qrow[i + 1] * kv.y + qrow[i + 2] * kv.z + qrow[i + 3] * kv.w;
  }
  dot *= 0.0883883476483184f;  // 1/sqrt(HD*4)
  if (mask && mask[((size_t)b * T + q) * T + k] == 0) dot = -1e30f;
  red[k] = dot;
  __syncthreads();
  for (int st = 256; st > 0; st >>= 1) {
    if (k < st) red[k] = fmaxf(red[k], red[k + st]);
    __syncthreads();
  }
  float mx = red[0];
  __syncthreads();
  float p = expf(dot - mx);
  red[k] = p;
  __syncthreads();
  for (int st = 256; st > 0; st >>= 1) {
    if (k < st) red[k] += red[k + st];
    __syncthreads();
  }
  float inv = 1.f / red[0];
  wout[(((size_t)(b * NH + h) * T + q)) * T + k] = p * inv;
}

// ---------------------------------------------------------------------------
// PV: o[b,q, h*HD + f, c] = sum_k w[b,h,q,k] * v[b,k, h*HD+f, c]
// grid (T, NH, B), block 128 (f*4+c)
__global__ __launch_bounds__(128) void attn_pv_kernel(
    const float* __restrict__ w, const float* __restrict__ vp, float* __restrict__ o) {
  int q = blockIdx.x, h = blockIdx.y, b = blockIdx.z;
  int fd = threadIdx.x;
  __shared__ float wrow[T];
  for (int i = threadIdx.x; i < T; i += 128)
    wrow[i] = w[(((size_t)(b * NH + h) * T + q)) * T + i];
  __syncthreads();
  const float* vbase = vp + ((size_t)b * T * D) * 4 + h * HD * 4 + fd;
  float acc = 0.f;
#pragma unroll 8
  for (int k = 0; k < T; ++k)
    acc += wrow[k] * vbase[(size_t)k * D * 4];
  o[(((size_t)b * T + q) * D + h * HD) * 4 + fd] = acc;
}

// ---------------------------------------------------------------------------
// x = g * ((x+y)/norm) + beta.   grid BT, block 256 (d)
__global__ __launch_bounds__(256) void resid_qnorm_kernel(
    float* __restrict__ x, const float* __restrict__ y,
    const float* __restrict__ g, const float* __restrict__ beta) {
  int n = blockIdx.x, d = threadIdx.x;
  size_t base = ((size_t)n * D + d) * 4;
  float4 xv = *(float4*)(x + base);
  float4 yv = *(const float4*)(y + base);
  float r = xv.x + yv.x, i = xv.y + yv.y, j = xv.z + yv.z, k = xv.w + yv.w;
  float nn = sqrtf(r * r + i * i + j * j + k * k + 1e-6f);
  float invn = 1.f / nn;
  float4 gv = ((const float4*)g)[d];
  float4 bv = ((const float4*)beta)[d];
  float4 res;
  res.x = gv.x * (r * invn) + bv.x;
  res.y = gv.y * (i * invn) + bv.y;
  res.z = gv.z * (j * invn) + bv.z;
  res.w = gv.w * (k * invn) + bv.w;
  *(float4*)(x + base) = res;
}

// ---------------------------------------------------------------------------
// modrelu in place on [BT, H, 4]. grid (BT, H/256), block 256
__global__ __launch_bounds__(256) void modrelu_kernel(
    float* __restrict__ x, const float* __restrict__ bias) {
  int n = blockIdx.x;
  int f = blockIdx.y * 256 + threadIdx.x;
  size_t base = ((size_t)n * H + f) * 4;
  float4 v = *(float4*)(x + base);
  float norm = sqrtf(v.x * v.x + v.y * v.y + v.z * v.z + v.w * v.w);
  float scale = fmaxf(norm + bias[f], 0.f) / (norm + 1e-6f);
  v.x *= scale; v.y *= scale; v.z *= scale; v.w *= scale;
  *(float4*)(x + base) = v;
}

// ---------------------------------------------------------------------------
// real[n,d] = |quat|  (no eps).  grid BT, block 256
__global__ __launch_bounds__(256) void to_real_kernel(
    const float* __restrict__ x, float* __restrict__ real) {
  int n = blockIdx.x, d = threadIdx.x;
  float4 v = ((const float4*)x)[(size_t)n * D + d];
  real[(size_t)n * D + d] = sqrtf(v.x * v.x + v.y * v.y + v.z * v.z + v.w * v.w);
}

// ---------------------------------------------------------------------------
// logits = real [BT,D] @ fc_W^T [D,V] + fc_b.  64x64 tile, 256 threads, 4x4 micro
__global__ __launch_bounds__(256) void logits_gemm_kernel(
    const float* __restrict__ A, const float* __restrict__ Wt,
    const float* __restrict__ bias, float* __restrict__ out) {
  __shared__ float As[64][65];
  __shared__ float Bs[64][65];
  int v0 = blockIdx.x * 64;
  int n0 = blockIdx.y * 64;
  int tid = threadIdx.x;
  int ty = tid >> 4, tx = tid & 15;
  float acc[4][4] = {{0.f}};
  for (int k0 = 0; k0 < D; k0 += 64) {
    for (int idx = tid; idx < 4096; idx += 256) {
      int r = idx >> 6, c = idx & 63;
      As[r][c] = A[(size_t)(n0 + r) * D + k0 + c];
      Bs[r][c] = Wt[(size_t)(v0 + r) * D + k0 + c];
    }
    __syncthreads();
    for (int dd = 0; dd < 64; ++dd) {
      float a[4], bv[4];
#pragma unroll
      for (int m = 0; m < 4; ++m) a[m] = As[ty * 4 + m][dd];
#pragma unroll
      for (int p = 0; p < 4; ++p) bv[p] = Bs[tx * 4 + p][dd];
#pragma unroll
      for (int m = 0; m < 4; ++m)
#pragma unroll
        for (int p = 0; p < 4; ++p) acc[m][p] += a[m] * bv[p];
    }
    __syncthreads();
  }
#pragma unroll
  for (int m = 0; m < 4; ++m)
#pragma unroll
    for (int p = 0; p < 4; ++p)
      out[(size_t)(n0 + ty * 4 + m) * V + v0 + tx * 4 + p] =
          acc[m][p] + bias[v0 + tx * 4 + p];
}

// ---------------------------------------------------------------------------
extern "C" void kernel_launch(void* const* d_in, const int* in_sizes, int n_in,
                              void* d_out, int out_size, void* d_ws, size_t ws_size,
                              hipStream_t stream) {
  const int*   src        = (const int*)d_in[0];
  const int*   tgt        = (const int*)d_in[1];
  const int*   tgt_mask   = (const int*)d_in[2];
  const float* emb        = (const float*)d_in[3];
  const float* enc_attn_W = (const float*)d_in[4];
  const float* enc_attn_b = (const float*)d_in[5];
  const float* enc_norm_g = (const float*)d_in[6];
  const float* enc_norm_b = (const float*)d_in[7];
  const float* enc_ff_W1  = (const float*)d_in[8];
  const float* enc_ff_b1  = (const float*)d_in[9];
  const float* enc_ff_mod = (const float*)d_in[10];
  const float* enc_ff_W2  = (const float*)d_in[11];
  const float* enc_ff_b2  = (const float*)d_in[12];
  const float* dec_sa_W   = (const float*)d_in[13];
  const float* dec_sa_b   = (const float*)d_in[14];
  const float* dec_ca_W   = (const float*)d_in[15];
  const float* dec_ca_b   = (const float*)d_in[16];
  const float* dec_norm_g = (const float*)d_in[17];
  const float* dec_norm_b = (const float*)d_in[18];
  const float* dec_ff_W1  = (const float*)d_in[19];
  const float* dec_ff_b1  = (const float*)d_in[20];
  const float* dec_ff_mod = (const float*)d_in[21];
  const float* dec_ff_W2  = (const float*)d_in[22];
  const float* dec_ff_b2  = (const float*)d_in[23];
  const float* fc_W       = (const float*)d_in[24];
  const float* fc_b       = (const float*)d_in[25];
  float* out = (float*)d_out;

  const size_t SZX = (size_t)BT * D * 4;      // 2,097,152 floats
  float* ws    = (float*)d_ws;
  float* xsrc  = ws;                // encoder state m
  float* xtgt  = xsrc + SZX;        // decoder state x
  float* qp    = xtgt + SZX;
  float* kp    = qp + SZX;
  float* vp    = kp + SZX;
  float* obuf  = vp + SZX;
  float* tbuf  = obuf + SZX;        // attn_out / ff_out
  float* hbuf  = tbuf + SZX;        // [BT, H, 4] = 8,388,608 floats
  float* wbuf  = hbuf + (size_t)BT * H * 4;   // [B,NH,T,T] = 8,388,608 floats
  float* realb = wbuf + (size_t)B * NH * T * T;

  auto qlinear = [&](const float* x, const float* W, const float* bb, float* o,
                     int Din, int Dout) {
    qlinear_kernel<<<dim3(BT, Dout / 256), 256, 0, stream>>>(x, W, bb, o, Din, Dout);
  };

  auto attention = [&](const float* qin, const float* kvin, const float* W,
                       const float* bb, const int* mask, float* outbuf) {
    qlinear(qin,  W + 0 * (size_t)4 * D * D, bb + 0 * (size_t)D * 4, qp, D, D);
    qlinear(kvin, W + 1 * (size_t)4 * D * D, bb + 1 * (size_t)D * 4, kp, D, D);
    qlinear(kvin, W + 2 * (size_t)4 * D * D, bb + 2 * (size_t)D * 4, vp, D, D);
    attn_scores_kernel<<<dim3(T, NH, B), 512, 0, stream>>>(qp, kp, mask, wbuf);
    attn_pv_kernel<<<dim3(T, NH, B), 128, 0, stream>>>(wbuf, vp, obuf);
    qlinear(obuf, W + 3 * (size_t)4 * D * D, bb + 3 * (size_t)D * 4, outbuf, D, D);
  };

  auto ff = [&](float* x, const float* W1, const float* b1, const float* mod,
                const float* W2, const float* b2, float* o) {
    qlinear(x, W1, b1, hbuf, D, H);
    modrelu_kernel<<<dim3(BT, H / 256), 256, 0, stream>>>(hbuf, mod);
    qlinear(hbuf, W2, b2, o, H, D);
  };

  embed_rope_kernel<<<BT, 256, 0, stream>>>(src, emb, xsrc);
  embed_rope_kernel<<<BT, 256, 0, stream>>>(tgt, emb, xtgt);

  // encoder
  for (int l = 0; l < LE; ++l) {
    const float* W  = enc_attn_W + (size_t)l * 16 * D * D;
    const float* bb = enc_attn_b + (size_t)l * 4 * D * 4;
    attention(xsrc, xsrc, W, bb, nullptr, tbuf);
    resid_qnorm_kernel<<<BT, 256, 0, stream>>>(
        xsrc, tbuf, enc_norm_g + (size_t)(l * 2 + 0) * D * 4,
        enc_norm_b + (size_t)(l * 2 + 0) * D * 4);
    ff(xsrc, enc_ff_W1 + (size_t)l * 4 * H * D, enc_ff_b1 + (size_t)l * H * 4,
       enc_ff_mod + (size_t)l * H, enc_ff_W2 + (size_t)l * 4 * D * H,
       enc_ff_b2 + (size_t)l * D * 4, tbuf);
    resid_qnorm_kernel<<<BT, 256, 0, stream>>>(
        xsrc, tbuf, enc_norm_g + (size_t)(l * 2 + 1) * D * 4,
        enc_norm_b + (size_t)(l * 2 + 1) * D * 4);
  }

  // decoder
  for (int l = 0; l < LD; ++l) {
    attention(xtgt, xtgt, dec_sa_W + (size_t)l * 16 * D * D,
              dec_sa_b + (size_t)l * 4 * D * 4, tgt_mask, tbuf);
    resid_qnorm_kernel<<<BT, 256, 0, stream>>>(
        xtgt, tbuf, dec_norm_g + (size_t)(l * 3 + 0) * D * 4,
        dec_norm_b + (size_t)(l * 3 + 0) * D * 4);
    attention(xtgt, xsrc, dec_ca_W + (size_t)l * 16 * D * D,
              dec_ca_b + (size_t)l * 4 * D * 4, nullptr, tbuf);
    resid_qnorm_kernel<<<BT, 256, 0, stream>>>(
        xtgt, tbuf, dec_norm_g + (size_t)(l * 3 + 1) * D * 4,
        dec_norm_b + (size_t)(l * 3 + 1) * D * 4);
    ff(xtgt, dec_ff_W1 + (size_t)l * 4 * H * D, dec_ff_b1 + (size_t)l * H * 4,
       dec_ff_mod + (size_t)l * H, dec_ff_W2 + (size_t)l * 4 * D * H,
       dec_ff_b2 + (size_t)l * D * 4, tbuf);
    resid_qnorm_kernel<<<BT, 256, 0, stream>>>(
        xtgt, tbuf, dec_norm_g + (size_t)(l * 3 + 2) * D * 4,
        dec_norm_b + (size_t)(l * 3 + 2) * D * 4);
  }

  to_real_kernel<<<BT, 256, 0, stream>>>(xtgt, realb);
  logits_gemm_kernel<<<dim3(V / 64, BT / 64), 256, 0, stream>>>(realb, fc_W, fc_b, out);
}

// Round 2
// 5110.666 us; speedup vs baseline: 6.4153x; 6.4153x over previous
//
#include <hip/hip_runtime.h>
#include <math.h>

#define B 4
#define T 512
#define D 256
#define H 1024
#define NH 8
#define HD 32
#define V 32000
#define BT (B*T)
#define LE 2
#define LD 2

typedef __attribute__((ext_vector_type(8))) short s16x8;
typedef __attribute__((ext_vector_type(4))) float f32x4;
typedef __attribute__((address_space(3))) void lds_void;
typedef const __attribute__((address_space(1))) void g_void;

__device__ __forceinline__ ushort f2bf(float x) {
  uint u = __float_as_uint(x);
  return (ushort)((u + 0x7fffu + ((u >> 16) & 1u)) >> 16);
}

// ---------------------------------------------------------------------------
// embed + rope fused: out [BT, D, 4]
__global__ __launch_bounds__(256) void embed_rope_kernel(
    const int* __restrict__ ids, const float* __restrict__ emb, float* __restrict__ out) {
  int bt = blockIdx.x;
  int d  = threadIdx.x;
  int id = ids[bt];
  int t  = bt % T;
  size_t VD = (size_t)V * D;
  float scale = powf(10000.f, -(float)d / (float)D);
  float r = emb[(size_t)id * D + d];
  float i = emb[VD + (size_t)id * D + d] * scale;
  float j = emb[2 * VD + (size_t)id * D + d] * scale;
  float k = emb[3 * VD + (size_t)id * D + d] * scale;
  float n = sqrtf(r * r + i * i + j * j + k * k + 1e-6f);
  float ang;
  if (d < D / 2) {
    float inv = powf(10000.f, -(float)(2 * d) / (float)D);
    ang = sinf((float)t * inv);
  } else {
    float inv = powf(10000.f, -(float)(2 * (d - D / 2)) / (float)D);
    ang = cosf((float)t * inv);
  }
  float s = ang / n;
  size_t base = ((size_t)bt * D + d) * 4;
  out[base + 0] = r * s;
  out[base + 1] = i * s;
  out[base + 2] = j * s;
  out[base + 3] = k * s;
}

// ---------------------------------------------------------------------------
// f32 -> bf16 convert, 4 elems/thread
__global__ __launch_bounds__(256) void f2bf_kernel(
    const float* __restrict__ in, ushort* __restrict__ out, int n4) {
  int i = blockIdx.x * 256 + threadIdx.x;
  if (i >= n4) return;
  float4 v = ((const float4*)in)[i];
  ushort4 o = make_ushort4(f2bf(v.x), f2bf(v.y), f2bf(v.z), f2bf(v.w));
  ((ushort4*)out)[i] = o;
}

// ---------------------------------------------------------------------------
// expand quaternion weight W [4, Dout, Din] f32 -> Wexp_t [4*Dout][4*Din] bf16
// Wexp_t[o*4+c][d*4+c'] = sign(c',c) * W[m(c',c)][o][d]  (B^T layout for GEMM)
__global__ __launch_bounds__(64) void qexpand_kernel(
    const float* __restrict__ W, ushort* __restrict__ Wt, int Dout, int Din) {
  int d = blockIdx.x * 64 + threadIdx.x;
  int o = blockIdx.y;
  size_t P = (size_t)Dout * Din;
  float w0 = W[(size_t)o * Din + d];
  float w1 = W[P + (size_t)o * Din + d];
  float w2 = W[2 * P + (size_t)o * Din + d];
  float w3 = W[3 * P + (size_t)o * Din + d];
  int K4 = Din * 4;
  size_t rbase = (size_t)(o * 4) * K4 + d * 4;
  // row c=0 (ro): +Wr -Wi -Wj -Wk ; c=1 (io): +Wi +Wr +Wk -Wj
  // row c=2 (jo): +Wj -Wk +Wr +Wi ; c=3 (ko): +Wk +Wj -Wi +Wr
  *(ushort4*)(Wt + rbase)          = make_ushort4(f2bf(w0), f2bf(-w1), f2bf(-w2), f2bf(-w3));
  *(ushort4*)(Wt + rbase + K4)     = make_ushort4(f2bf(w1), f2bf(w0),  f2bf(w3),  f2bf(-w2));
  *(ushort4*)(Wt + rbase + 2 * K4) = make_ushort4(f2bf(w2), f2bf(-w3), f2bf(w0),  f2bf(w1));
  *(ushort4*)(Wt + rbase + 3 * K4) = make_ushort4(f2bf(w3), f2bf(w2),  f2bf(-w1), f2bf(w0));
}

// ---------------------------------------------------------------------------
// C[M,N] f32 = A[M,K]bf16 * Bt[N,K]bf16^T + bias[N]
// 128x128 tile, 256 threads (4 waves 2x2), BK=32, mfma 16x16x32, m97-style.
__global__ __launch_bounds__(256) void gemm_bf16_kernel(
    const ushort* __restrict__ A, const ushort* __restrict__ Bt,
    const float* __restrict__ bias, float* __restrict__ C, int N, int K) {
  __shared__ ushort As[128 * 32];
  __shared__ ushort Bs[128 * 32];
  const int tid = threadIdx.x;
  const int w = tid >> 6, l = tid & 63;
  const int wm = w >> 1, wn = w & 1;
  const int m0 = blockIdx.y * 128, n0 = blockIdx.x * 128;
  const int lr = l & 15, lg = l >> 4;
  f32x4 acc[4][4] = {};
  for (int k0 = 0; k0 < K; k0 += 32) {
    if (k0) __syncthreads();  // previous reads done before overwrite
#pragma unroll
    for (int s = 0; s < 2; ++s) {
      int fb = (w * 2 + s) * 1024;     // wave-uniform LDS byte base
      int f = fb + l * 16;             // this lane's byte offset in tile
      int row = f >> 6, cb = f & 63;   // 64B per row (32 bf16)
      const ushort* asrc = A + (size_t)(m0 + row) * K + k0 + (cb >> 1);
      const ushort* bsrc = Bt + (size_t)(n0 + row) * K + k0 + (cb >> 1);
      __builtin_amdgcn_global_load_lds((g_void*)asrc, (lds_void*)((char*)As + fb), 16, 0, 0);
      __builtin_amdgcn_global_load_lds((g_void*)bsrc, (lds_void*)((char*)Bs + fb), 16, 0, 0);
    }
    __syncthreads();  // staging complete (barrier drains vmcnt)
    s16x8 af[4], bfr[4];
#pragma unroll
    for (int mi = 0; mi < 4; ++mi)
      af[mi] = *(const s16x8*)(As + (wm * 64 + mi * 16 + lr) * 32 + lg * 8);
#pragma unroll
    for (int ni = 0; ni < 4; ++ni)
      bfr[ni] = *(const s16x8*)(Bs + (wn * 64 + ni * 16 + lr) * 32 + lg * 8);
#pragma unroll
    for (int mi = 0; mi < 4; ++mi)
#pragma unroll
      for (int ni = 0; ni < 4; ++ni)
        acc[mi][ni] = __builtin_amdgcn_mfma_f32_16x16x32_bf16(af[mi], bfr[ni], acc[mi][ni], 0, 0, 0);
  }
#pragma unroll
  for (int mi = 0; mi < 4; ++mi) {
#pragma unroll
    for (int ni = 0; ni < 4; ++ni) {
      int row = m0 + wm * 64 + mi * 16 + lg * 4;
      int col = n0 + wn * 64 + ni * 16 + lr;
      float bv = bias ? bias[col] : 0.f;
      f32x4 v = acc[mi][ni];
#pragma unroll
      for (int r = 0; r < 4; ++r)
        C[(size_t)(row + r) * N + col] = v[r] + bv;
    }
  }
}

// ---------------------------------------------------------------------------
// scores + softmax. grid (T, NH, B), block 512 (one thread per key)
__global__ __launch_bounds__(512) void attn_scores_kernel(
    const float* __restrict__ qp, const float* __restrict__ kp,
    const int* __restrict__ mask, float* __restrict__ wout) {
  int q = blockIdx.x, h = blockIdx.y, b = blockIdx.z;
  int k = threadIdx.x;
  __shared__ float qrow[128];
  __shared__ float red[512];
  if (k < 128) qrow[k] = qp[(((size_t)b * T + q) * D + h * HD) * 4 + k];
  __syncthreads();
  const float* kptr = kp + (((size_t)b * T + k) * D + h * HD) * 4;
  float dot = 0.f;
#pragma unroll
  for (int i = 0; i < 128; i += 4) {
    float4 kv = *(const float4*)(kptr + i);
    dot += qrow[i] * kv.x + qrow[i + 1] * kv.y + qrow[i + 2] * kv.z + qrow[i + 3] * kv.w;
  }
  dot *= 0.0883883476483184f;  // 1/sqrt(HD*4)
  if (mask && mask[((size_t)b * T + q) * T + k] == 0) dot = -1e30f;
  red[k] = dot;
  __syncthreads();
  for (int st = 256; st > 0; st >>= 1) {
    if (k < st) red[k] = fmaxf(red[k], red[k + st]);
    __syncthreads();
  }
  float mx = red[0];
  __syncthreads();
  float p = expf(dot - mx);
  red[k] = p;
  __syncthreads();
  for (int st = 256; st > 0; st >>= 1) {
    if (k < st) red[k] += red[k + st];
    __syncthreads();
  }
  float inv = 1.f / red[0];
  wout[(((size_t)(b * NH + h) * T + q)) * T + k] = p * inv;
}

// ---------------------------------------------------------------------------
// PV: o[b,q, h*HD + f, c] = sum_k w[b,h,q,k] * v[b,k, h*HD+f, c]
__global__ __launch_bounds__(128) void attn_pv_kernel(
    const float* __restrict__ w, const float* __restrict__ vp, float* __restrict__ o) {
  int q = blockIdx.x, h = blockIdx.y, b = blockIdx.z;
  int fd = threadIdx.x;
  __shared__ float wrow[T];
  for (int i = threadIdx.x; i < T; i += 128)
    wrow[i] = w[(((size_t)(b * NH + h) * T + q)) * T + i];
  __syncthreads();
  const float* vbase = vp + ((size_t)b * T * D) * 4 + h * HD * 4 + fd;
  float acc = 0.f;
#pragma unroll 8
  for (int k = 0; k < T; ++k)
    acc += wrow[k] * vbase[(size_t)k * D * 4];
  o[(((size_t)b * T + q) * D + h * HD) * 4 + fd] = acc;
}

// ---------------------------------------------------------------------------
__global__ __launch_bounds__(256) void resid_qnorm_kernel(
    float* __restrict__ x, const float* __restrict__ y,
    const float* __restrict__ g, const float* __restrict__ beta) {
  int n = blockIdx.x, d = threadIdx.x;
  size_t base = ((size_t)n * D + d) * 4;
  float4 xv = *(float4*)(x + base);
  float4 yv = *(const float4*)(y + base);
  float r = xv.x + yv.x, i = xv.y + yv.y, j = xv.z + yv.z, k = xv.w + yv.w;
  float nn = sqrtf(r * r + i * i + j * j + k * k + 1e-6f);
  float invn = 1.f / nn;
  float4 gv = ((const float4*)g)[d];
  float4 bv = ((const float4*)beta)[d];
  float4 res;
  res.x = gv.x * (r * invn) + bv.x;
  res.y = gv.y * (i * invn) + bv.y;
  res.z = gv.z * (j * invn) + bv.z;
  res.w = gv.w * (k * invn) + bv.w;
  *(float4*)(x + base) = res;
}

// ---------------------------------------------------------------------------
__global__ __launch_bounds__(256) void modrelu_kernel(
    float* __restrict__ x, const float* __restrict__ bias) {
  int n = blockIdx.x;
  int f = blockIdx.y * 256 + threadIdx.x;
  size_t base = ((size_t)n * H + f) * 4;
  float4 v = *(float4*)(x + base);
  float norm = sqrtf(v.x * v.x + v.y * v.y + v.z * v.z + v.w * v.w);
  float scale = fmaxf(norm + bias[f], 0.f) / (norm + 1e-6f);
  v.x *= scale; v.y *= scale; v.z *= scale; v.w *= scale;
  *(float4*)(x + base) = v;
}

// ---------------------------------------------------------------------------
__global__ __launch_bounds__(256) void to_real_kernel(
    const float* __restrict__ x, float* __restrict__ real) {
  int n = blockIdx.x, d = threadIdx.x;
  float4 v = ((const float4*)x)[(size_t)n * D + d];
  real[(size_t)n * D + d] = sqrtf(v.x * v.x + v.y * v.y + v.z * v.z + v.w * v.w);
}

// ---------------------------------------------------------------------------
extern "C" void kernel_launch(void* const* d_in, const int* in_sizes, int n_in,
                              void* d_out, int out_size, void* d_ws, size_t ws_size,
                              hipStream_t stream) {
  const int*   src        = (const int*)d_in[0];
  const int*   tgt        = (const int*)d_in[1];
  const int*   tgt_mask   = (const int*)d_in[2];
  const float* emb        = (const float*)d_in[3];
  const float* enc_attn_W = (const float*)d_in[4];
  const float* enc_attn_b = (const float*)d_in[5];
  const float* enc_norm_g = (const float*)d_in[6];
  const float* enc_norm_b = (const float*)d_in[7];
  const float* enc_ff_W1  = (const float*)d_in[8];
  const float* enc_ff_b1  = (const float*)d_in[9];
  const float* enc_ff_mod = (const float*)d_in[10];
  const float* enc_ff_W2  = (const float*)d_in[11];
  const float* enc_ff_b2  = (const float*)d_in[12];
  const float* dec_sa_W   = (const float*)d_in[13];
  const float* dec_sa_b   = (const float*)d_in[14];
  const float* dec_ca_W   = (const float*)d_in[15];
  const float* dec_ca_b   = (const float*)d_in[16];
  const float* dec_norm_g = (const float*)d_in[17];
  const float* dec_norm_b = (const float*)d_in[18];
  const float* dec_ff_W1  = (const float*)d_in[19];
  const float* dec_ff_b1  = (const float*)d_in[20];
  const float* dec_ff_mod = (const float*)d_in[21];
  const float* dec_ff_W2  = (const float*)d_in[22];
  const float* dec_ff_b2  = (const float*)d_in[23];
  const float* fc_W       = (const float*)d_in[24];
  const float* fc_b       = (const float*)d_in[25];
  float* out = (float*)d_out;

  const size_t SZX = (size_t)BT * D * 4;  // 2,097,152
  float* ws    = (float*)d_ws;
  float* xsrc  = ws;
  float* xtgt  = xsrc + SZX;
  float* qp    = xtgt + SZX;
  float* kp    = qp + SZX;
  float* vp    = kp + SZX;
  float* obuf  = vp + SZX;
  float* tbuf  = obuf + SZX;
  float* hbuf  = tbuf + SZX;                    // [BT,4H] = 8,388,608 f
  float* wbuf  = hbuf + (size_t)BT * H * 4;     // 8,388,608 f
  float* realb = wbuf + (size_t)B * NH * T * T; // 524,288 f
  ushort* Abf  = (ushort*)(realb + (size_t)BT * D);  // up to 8,388,608 bf16
  ushort* Wexp = (ushort*)((float*)(void*)Abf + 4194304);  // up to 8,192,000 bf16

  auto conv = [&](const float* s, ushort* dst, size_t n) {
    int n4 = (int)(n / 4);
    f2bf_kernel<<<(n4 + 255) / 256, 256, 0, stream>>>(s, dst, n4);
  };
  auto expand = [&](const float* Wq, int Dout, int Din) {
    qexpand_kernel<<<dim3(Din / 64, Dout), 64, 0, stream>>>(Wq, Wexp, Dout, Din);
  };
  auto gemm = [&](const ushort* Ab, const ushort* Bt, const float* bias,
                  float* Cc, int M, int N, int K) {
    gemm_bf16_kernel<<<dim3(N / 128, M / 128), 256, 0, stream>>>(Ab, Bt, bias, Cc, N, K);
  };

  auto attention = [&](const float* qin, const float* kvin, const float* W,
                       const float* bb, const int* mask, float* outbuf) {
    conv(qin, Abf, SZX);
    expand(W + 0 * (size_t)4 * D * D, D, D);
    gemm(Abf, Wexp, bb + 0 * (size_t)D * 4, qp, BT, 4 * D, 4 * D);
    if (kvin != qin) conv(kvin, Abf, SZX);
    expand(W + 1 * (size_t)4 * D * D, D, D);
    gemm(Abf, Wexp, bb + 1 * (size_t)D * 4, kp, BT, 4 * D, 4 * D);
    expand(W + 2 * (size_t)4 * D * D, D, D);
    gemm(Abf, Wexp, bb + 2 * (size_t)D * 4, vp, BT, 4 * D, 4 * D);
    attn_scores_kernel<<<dim3(T, NH, B), 512, 0, stream>>>(qp, kp, mask, wbuf);
    attn_pv_kernel<<<dim3(T, NH, B), 128, 0, stream>>>(wbuf, vp, obuf);
    conv(obuf, Abf, SZX);
    expand(W + 3 * (size_t)4 * D * D, D, D);
    gemm(Abf, Wexp, bb + 3 * (size_t)D * 4, outbuf, BT, 4 * D, 4 * D);
  };

  auto ff = [&](float* x, const float* W1, const float* b1, const float* mod,
                const float* W2, const float* b2, float* o) {
    conv(x, Abf, SZX);
    expand(W1, H, D);
    gemm(Abf, Wexp, b1, hbuf, BT, 4 * H, 4 * D);
    modrelu_kernel<<<dim3(BT, H / 256), 256, 0, stream>>>(hbuf, mod);
    conv(hbuf, Abf, (size_t)BT * H * 4);
    expand(W2, D, H);
    gemm(Abf, Wexp, b2, o, BT, 4 * D, 4 * H);
  };

  embed_rope_kernel<<<BT, 256, 0, stream>>>(src, emb, xsrc);
  embed_rope_kernel<<<BT, 256, 0, stream>>>(tgt, emb, xtgt);

  for (int l = 0; l < LE; ++l) {
    attention(xsrc, xsrc, enc_attn_W + (size_t)l * 16 * D * D,
              enc_attn_b + (size_t)l * 4 * D * 4, nullptr, tbuf);
    resid_qnorm_kernel<<<BT, 256, 0, stream>>>(
        xsrc, tbuf, enc_norm_g + (size_t)(l * 2 + 0) * D * 4,
        enc_norm_b + (size_t)(l * 2 + 0) * D * 4);
    ff(xsrc, enc_ff_W1 + (size_t)l * 4 * H * D, enc_ff_b1 + (size_t)l * H * 4,
       enc_ff_mod + (size_t)l * H, enc_ff_W2 + (size_t)l * 4 * D * H,
       enc_ff_b2 + (size_t)l * D * 4, tbuf);
    resid_qnorm_kernel<<<BT, 256, 0, stream>>>(
        xsrc, tbuf, enc_norm_g + (size_t)(l * 2 + 1) * D * 4,
        enc_norm_b + (size_t)(l * 2 + 1) * D * 4);
  }

  for (int l = 0; l < LD; ++l) {
    attention(xtgt, xtgt, dec_sa_W + (size_t)l * 16 * D * D,
              dec_sa_b + (size_t)l * 4 * D * 4, tgt_mask, tbuf);
    resid_qnorm_kernel<<<BT, 256, 0, stream>>>(
        xtgt, tbuf, dec_norm_g + (size_t)(l * 3 + 0) * D * 4,
        dec_norm_b + (size_t)(l * 3 + 0) * D * 4);
    attention(xtgt, xsrc, dec_ca_W + (size_t)l * 16 * D * D,
              dec_ca_b + (size_t)l * 4 * D * 4, nullptr, tbuf);
    resid_qnorm_kernel<<<BT, 256, 0, stream>>>(
        xtgt, tbuf, dec_norm_g + (size_t)(l * 3 + 1) * D * 4,
        dec_norm_b + (size_t)(l * 3 + 1) * D * 4);
    ff(xtgt, dec_ff_W1 + (size_t)l * 4 * H * D, dec_ff_b1 + (size_t)l * H * 4,
       dec_ff_mod + (size_t)l * H, dec_ff_W2 + (size_t)l * 4 * D * H,
       dec_ff_b2 + (size_t)l * D * 4, tbuf);
    resid_qnorm_kernel<<<BT, 256, 0, stream>>>(
        xtgt, tbuf, dec_norm_g + (size_t)(l * 3 + 2) * D * 4,
        dec_norm_b + (size_t)(l * 3 + 2) * D * 4);
  }

  to_real_kernel<<<BT, 256, 0, stream>>>(xtgt, realb);
  conv(realb, Abf, (size_t)BT * D);
  conv(fc_W, Wexp, (size_t)V * D);
  gemm(Abf, Wexp, fc_b, out, BT, V, D);
}

// Round 3
// 1415.189 us; speedup vs baseline: 23.1675x; 3.6113x over previous
//
#include <hip/hip_runtime.h>
#include <math.h>

#define B 4
#define T 512
#define D 256
#define H 1024
#define NH 8
#define HD 32
#define V 32000
#define BT (B*T)
#define LE 2
#define LD 2

typedef __attribute__((ext_vector_type(8))) short s16x8;
typedef __attribute__((ext_vector_type(4))) float f32x4;
typedef __attribute__((address_space(3))) void lds_void;
typedef const __attribute__((address_space(1))) void g_void;

__device__ __forceinline__ ushort f2bf(float x) {
  uint u = __float_as_uint(x);
  return (ushort)((u + 0x7fffu + ((u >> 16) & 1u)) >> 16);
}

// ---------------------------------------------------------------------------
// embed + rope fused: out [BT, D, 4]
__global__ __launch_bounds__(256) void embed_rope_kernel(
    const int* __restrict__ ids, const float* __restrict__ emb, float* __restrict__ out) {
  int bt = blockIdx.x;
  int d  = threadIdx.x;
  int id = ids[bt];
  int t  = bt % T;
  size_t VD = (size_t)V * D;
  float scale = powf(10000.f, -(float)d / (float)D);
  float r = emb[(size_t)id * D + d];
  float i = emb[VD + (size_t)id * D + d] * scale;
  float j = emb[2 * VD + (size_t)id * D + d] * scale;
  float k = emb[3 * VD + (size_t)id * D + d] * scale;
  float n = sqrtf(r * r + i * i + j * j + k * k + 1e-6f);
  float ang;
  if (d < D / 2) {
    float inv = powf(10000.f, -(float)(2 * d) / (float)D);
    ang = sinf((float)t * inv);
  } else {
    float inv = powf(10000.f, -(float)(2 * (d - D / 2)) / (float)D);
    ang = cosf((float)t * inv);
  }
  float s = ang / n;
  size_t base = ((size_t)bt * D + d) * 4;
  out[base + 0] = r * s;
  out[base + 1] = i * s;
  out[base + 2] = j * s;
  out[base + 3] = k * s;
}

// ---------------------------------------------------------------------------
__global__ __launch_bounds__(256) void f2bf_kernel(
    const float* __restrict__ in, ushort* __restrict__ out, int n4) {
  int i = blockIdx.x * 256 + threadIdx.x;
  if (i >= n4) return;
  float4 v = ((const float4*)in)[i];
  ushort4 o = make_ushort4(f2bf(v.x), f2bf(v.y), f2bf(v.z), f2bf(v.w));
  ((ushort4*)out)[i] = o;
}

// ---------------------------------------------------------------------------
// expand quaternion weight W [4, Dout, Din] f32 -> Wexp_t [4*Dout][4*Din] bf16
__global__ __launch_bounds__(64) void qexpand_kernel(
    const float* __restrict__ W, ushort* __restrict__ Wt, int Dout, int Din) {
  int d = blockIdx.x * 64 + threadIdx.x;
  int o = blockIdx.y;
  size_t P = (size_t)Dout * Din;
  float w0 = W[(size_t)o * Din + d];
  float w1 = W[P + (size_t)o * Din + d];
  float w2 = W[2 * P + (size_t)o * Din + d];
  float w3 = W[3 * P + (size_t)o * Din + d];
  int K4 = Din * 4;
  size_t rbase = (size_t)(o * 4) * K4 + d * 4;
  *(ushort4*)(Wt + rbase)          = make_ushort4(f2bf(w0), f2bf(-w1), f2bf(-w2), f2bf(-w3));
  *(ushort4*)(Wt + rbase + K4)     = make_ushort4(f2bf(w1), f2bf(w0),  f2bf(w3),  f2bf(-w2));
  *(ushort4*)(Wt + rbase + 2 * K4) = make_ushort4(f2bf(w2), f2bf(-w3), f2bf(w0),  f2bf(w1));
  *(ushort4*)(Wt + rbase + 3 * K4) = make_ushort4(f2bf(w3), f2bf(w2),  f2bf(-w1), f2bf(w0));
}

// ---------------------------------------------------------------------------
// C[M,N] = A[M,K]bf16 * Bt[N,K]bf16^T + bias[N]
// OMODE: 0 = f32 out, 1 = bf16 out, 2 = bf16 transposed-V out ([b,h,d][T])
template <int OMODE>
__global__ __launch_bounds__(256) void gemm_bf16_kernel(
    const ushort* __restrict__ A, const ushort* __restrict__ Bt,
    const float* __restrict__ bias, void* __restrict__ Cv, int N, int K) {
  __shared__ ushort As[128 * 32];
  __shared__ ushort Bs[128 * 32];
  const int tid = threadIdx.x;
  const int w = tid >> 6, l = tid & 63;
  const int wm = w >> 1, wn = w & 1;
  const int m0 = blockIdx.y * 128, n0 = blockIdx.x * 128;
  const int lr = l & 15, lg = l >> 4;
  f32x4 acc[4][4] = {};
  for (int k0 = 0; k0 < K; k0 += 32) {
    if (k0) __syncthreads();
#pragma unroll
    for (int s = 0; s < 2; ++s) {
      int fb = (w * 2 + s) * 1024;
      int f = fb + l * 16;
      int row = f >> 6, cb = f & 63;
      const ushort* asrc = A + (size_t)(m0 + row) * K + k0 + (cb >> 1);
      const ushort* bsrc = Bt + (size_t)(n0 + row) * K + k0 + (cb >> 1);
      __builtin_amdgcn_global_load_lds((g_void*)asrc, (lds_void*)((char*)As + fb), 16, 0, 0);
      __builtin_amdgcn_global_load_lds((g_void*)bsrc, (lds_void*)((char*)Bs + fb), 16, 0, 0);
    }
    __syncthreads();
    s16x8 af[4], bfr[4];
#pragma unroll
    for (int mi = 0; mi < 4; ++mi)
      af[mi] = *(const s16x8*)(As + (wm * 64 + mi * 16 + lr) * 32 + lg * 8);
#pragma unroll
    for (int ni = 0; ni < 4; ++ni)
      bfr[ni] = *(const s16x8*)(Bs + (wn * 64 + ni * 16 + lr) * 32 + lg * 8);
#pragma unroll
    for (int mi = 0; mi < 4; ++mi)
#pragma unroll
      for (int ni = 0; ni < 4; ++ni)
        acc[mi][ni] = __builtin_amdgcn_mfma_f32_16x16x32_bf16(af[mi], bfr[ni], acc[mi][ni], 0, 0, 0);
  }
#pragma unroll
  for (int mi = 0; mi < 4; ++mi) {
#pragma unroll
    for (int ni = 0; ni < 4; ++ni) {
      int row = m0 + wm * 64 + mi * 16 + lg * 4;
      int col = n0 + wn * 64 + ni * 16 + lr;
      float bv = bias ? bias[col] : 0.f;
      f32x4 v = acc[mi][ni];
      if constexpr (OMODE == 0) {
        float* C = (float*)Cv;
#pragma unroll
        for (int r = 0; r < 4; ++r)
          C[(size_t)(row + r) * N + col] = v[r] + bv;
      } else if constexpr (OMODE == 1) {
        ushort* C = (ushort*)Cv;
#pragma unroll
        for (int r = 0; r < 4; ++r)
          C[(size_t)(row + r) * N + col] = f2bf(v[r] + bv);
      } else {
        // transposed V: out[(b*1024 + col)*T + t], t = row&511, b = row>>9
        ushort* C = (ushort*)Cv;
        ushort4 o = make_ushort4(f2bf(v[0] + bv), f2bf(v[1] + bv),
                                 f2bf(v[2] + bv), f2bf(v[3] + bv));
        *(ushort4*)&C[((size_t)((row >> 9) << 10) + col) * T + (row & 511)] = o;
      }
    }
  }
}

// ---------------------------------------------------------------------------
// fused flash attention, head-dim 128. grid (T/64, NH, B), 4 waves, each 16 q-rows.
// qb,kb: [BT][512] bf16 ; vT: [(b*NH+h)*128+d][T] bf16 ; outA: [BT][512] bf16
__global__ __launch_bounds__(256) void fused_attn_kernel(
    const ushort* __restrict__ qb, const ushort* __restrict__ kb,
    const ushort* __restrict__ vT, ushort* __restrict__ outA, int causal) {
  __shared__ ushort Pst[4][1024];
  const int tid = threadIdx.x;
  const int wq = tid >> 6, l = tid & 63;
  const int lr = l & 15, lg = l >> 4;
  const int h = blockIdx.y, b = blockIdx.z;
  const int q0 = blockIdx.x * 64 + wq * 16;
  const size_t bT = (size_t)b * T;
  const int hc = h * 128;
  s16x8 qf[4];
#pragma unroll
  for (int ks = 0; ks < 4; ++ks)
    qf[ks] = *(const s16x8*)(qb + (bT + q0 + lr) * 512 + hc + ks * 32 + lg * 8);
  f32x4 O[8] = {};
  float m[4] = {-3e38f, -3e38f, -3e38f, -3e38f};
  float lac[4] = {0.f, 0.f, 0.f, 0.f};
  const int kend = causal ? ((q0 + 79) & ~63) : T;
  const ushort* vbase = vT + ((size_t)(b * NH + h) * 128) * T;
  for (int kv0 = 0; kv0 < kend; kv0 += 64) {
    f32x4 s[4] = {};
#pragma unroll
    for (int ks = 0; ks < 4; ++ks) {
      s16x8 kf[4];
#pragma unroll
      for (int ni = 0; ni < 4; ++ni)
        kf[ni] = *(const s16x8*)(kb + (bT + kv0 + ni * 16 + lr) * 512 + hc + ks * 32 + lg * 8);
#pragma unroll
      for (int ni = 0; ni < 4; ++ni)
        s[ni] = __builtin_amdgcn_mfma_f32_16x16x32_bf16(qf[ks], kf[ni], s[ni], 0, 0, 0);
    }
    const bool domask = causal && (kv0 + 63 > q0);
#pragma unroll
    for (int r = 0; r < 4; ++r) {
      const int qrow = q0 + lg * 4 + r;
      float mx = -3e38f;
#pragma unroll
      for (int ni = 0; ni < 4; ++ni) {
        float v = s[ni][r] * 0.08838834764831845f;
        if (domask && (kv0 + ni * 16 + lr > qrow)) v = -3e38f;
        s[ni][r] = v;
        mx = fmaxf(mx, v);
      }
#pragma unroll
      for (int dd = 1; dd < 16; dd <<= 1) mx = fmaxf(mx, __shfl_xor(mx, dd));
      float mn = fmaxf(m[r], mx);
      float alpha = __expf(m[r] - mn);
      m[r] = mn;
      float ps = 0.f;
#pragma unroll
      for (int ni = 0; ni < 4; ++ni) {
        float p = __expf(s[ni][r] - mn);
        s[ni][r] = p;
        ps += p;
      }
#pragma unroll
      for (int dd = 1; dd < 16; dd <<= 1) ps += __shfl_xor(ps, dd);
      lac[r] = lac[r] * alpha + ps;
#pragma unroll
      for (int dni = 0; dni < 8; ++dni) O[dni][r] *= alpha;
      const int qloc = lg * 4 + r;
      const int sw = (qloc & 7) << 3;
#pragma unroll
      for (int ni = 0; ni < 4; ++ni)
        Pst[wq][qloc * 64 + ((ni * 16 + lr) ^ sw)] = f2bf(s[ni][r]);
    }
#pragma unroll
    for (int ks2 = 0; ks2 < 2; ++ks2) {
      s16x8 pa = *(const s16x8*)&Pst[wq][lr * 64 + ((ks2 * 32 + lg * 8) ^ ((lr & 7) << 3))];
#pragma unroll
      for (int dni = 0; dni < 8; ++dni) {
        s16x8 vf = *(const s16x8*)(vbase + (size_t)(dni * 16 + lr) * T + kv0 + ks2 * 32 + lg * 8);
        O[dni] = __builtin_amdgcn_mfma_f32_16x16x32_bf16(pa, vf, O[dni], 0, 0, 0);
      }
    }
  }
#pragma unroll
  for (int r = 0; r < 4; ++r) {
    float inv = 1.f / lac[r];
    const size_t row = bT + q0 + lg * 4 + r;
#pragma unroll
    for (int dni = 0; dni < 8; ++dni)
      outA[row * 512 + hc + dni * 16 + lr] = f2bf(O[dni][r] * inv);
  }
}

// ---------------------------------------------------------------------------
__global__ __launch_bounds__(256) void resid_qnorm_kernel(
    float* __restrict__ x, const float* __restrict__ y,
    const float* __restrict__ g, const float* __restrict__ beta) {
  int n = blockIdx.x, d = threadIdx.x;
  size_t base = ((size_t)n * D + d) * 4;
  float4 xv = *(float4*)(x + base);
  float4 yv = *(const float4*)(y + base);
  float r = xv.x + yv.x, i = xv.y + yv.y, j = xv.z + yv.z, k = xv.w + yv.w;
  float nn = sqrtf(r * r + i * i + j * j + k * k + 1e-6f);
  float invn = 1.f / nn;
  float4 gv = ((const float4*)g)[d];
  float4 bv = ((const float4*)beta)[d];
  float4 res;
  res.x = gv.x * (r * invn) + bv.x;
  res.y = gv.y * (i * invn) + bv.y;
  res.z = gv.z * (j * invn) + bv.z;
  res.w = gv.w * (k * invn) + bv.w;
  *(float4*)(x + base) = res;
}

// ---------------------------------------------------------------------------
__global__ __launch_bounds__(256) void modrelu_kernel(
    float* __restrict__ x, const float* __restrict__ bias) {
  int n = blockIdx.x;
  int f = blockIdx.y * 256 + threadIdx.x;
  size_t base = ((size_t)n * H + f) * 4;
  float4 v = *(float4*)(x + base);
  float norm = sqrtf(v.x * v.x + v.y * v.y + v.z * v.z + v.w * v.w);
  float scale = fmaxf(norm + bias[f], 0.f) / (norm + 1e-6f);
  v.x *= scale; v.y *= scale; v.z *= scale; v.w *= scale;
  *(float4*)(x + base) = v;
}

// ---------------------------------------------------------------------------
__global__ __launch_bounds__(256) void to_real_kernel(
    const float* __restrict__ x, float* __restrict__ real) {
  int n = blockIdx.x, d = threadIdx.x;
  float4 v = ((const float4*)x)[(size_t)n * D + d];
  real[(size_t)n * D + d] = sqrtf(v.x * v.x + v.y * v.y + v.z * v.z + v.w * v.w);
}

// ---------------------------------------------------------------------------
extern "C" void kernel_launch(void* const* d_in, const int* in_sizes, int n_in,
                              void* d_out, int out_size, void* d_ws, size_t ws_size,
                              hipStream_t stream) {
  const int*   src        = (const int*)d_in[0];
  const int*   tgt        = (const int*)d_in[1];
  const float* emb        = (const float*)d_in[3];
  const float* enc_attn_W = (const float*)d_in[4];
  const float* enc_attn_b = (const float*)d_in[5];
  const float* enc_norm_g = (const float*)d_in[6];
  const float* enc_norm_b = (const float*)d_in[7];
  const float* enc_ff_W1  = (const float*)d_in[8];
  const float* enc_ff_b1  = (const float*)d_in[9];
  const float* enc_ff_mod = (const float*)d_in[10];
  const float* enc_ff_W2  = (const float*)d_in[11];
  const float* enc_ff_b2  = (const float*)d_in[12];
  const float* dec_sa_W   = (const float*)d_in[13];
  const float* dec_sa_b   = (const float*)d_in[14];
  const float* dec_ca_W   = (const float*)d_in[15];
  const float* dec_ca_b   = (const float*)d_in[16];
  const float* dec_norm_g = (const float*)d_in[17];
  const float* dec_norm_b = (const float*)d_in[18];
  const float* dec_ff_W1  = (const float*)d_in[19];
  const float* dec_ff_b1  = (const float*)d_in[20];
  const float* dec_ff_mod = (const float*)d_in[21];
  const float* dec_ff_W2  = (const float*)d_in[22];
  const float* dec_ff_b2  = (const float*)d_in[23];
  const float* fc_W       = (const float*)d_in[24];
  const float* fc_b       = (const float*)d_in[25];
  float* out = (float*)d_out;

  const size_t SZX = (size_t)BT * D * 4;  // 2,097,152 floats
  float* ws    = (float*)d_ws;
  float* xsrc  = ws;
  float* xtgt  = xsrc + SZX;
  float* tbuf  = xtgt + SZX;
  float* hbuf  = tbuf + SZX;                    // BT*4H = 8,388,608 f
  float* realb = hbuf + (size_t)BT * H * 4;     // 524,288 f
  ushort* Abf  = (ushort*)(realb + (size_t)BT * D);   // 8,388,608 bf16
  ushort* Wexp = Abf + (size_t)BT * H * 4;            // 8,192,000 bf16
  ushort* qb   = Wexp + (size_t)V * D;                // 1,048,576 bf16
  ushort* kb   = qb + (size_t)BT * 512;
  ushort* vTb  = kb + (size_t)BT * 512;               // 2,097,152 bf16 ([b,h,d][T])

  auto conv = [&](const float* s, ushort* dst, size_t n) {
    int n4 = (int)(n / 4);
    f2bf_kernel<<<(n4 + 255) / 256, 256, 0, stream>>>(s, dst, n4);
  };
  auto expand = [&](const float* Wq, int Dout, int Din) {
    qexpand_kernel<<<dim3(Din / 64, Dout), 64, 0, stream>>>(Wq, Wexp, Dout, Din);
  };
  auto gemm_f = [&](const ushort* Ab, const float* bias, float* Cc, int M, int N, int K) {
    gemm_bf16_kernel<0><<<dim3(N / 128, M / 128), 256, 0, stream>>>(Ab, Wexp, bias, Cc, N, K);
  };
  auto gemm_b = [&](const ushort* Ab, const float* bias, ushort* Cc, int M, int N, int K) {
    gemm_bf16_kernel<1><<<dim3(N / 128, M / 128), 256, 0, stream>>>(Ab, Wexp, bias, Cc, N, K);
  };
  auto gemm_v = [&](const ushort* Ab, const float* bias, ushort* Cc, int M, int N, int K) {
    gemm_bf16_kernel<2><<<dim3(N / 128, M / 128), 256, 0, stream>>>(Ab, Wexp, bias, Cc, N, K);
  };

  const size_t DD4 = (size_t)4 * D * D;
  auto attention = [&](const float* qin, const float* kvin, const float* W,
                       const float* bb, int causal, float* outbuf) {
    conv(qin, Abf, SZX);
    expand(W + 0 * DD4, D, D);
    gemm_b(Abf, bb + 0 * (size_t)D * 4, qb, BT, 512, 512);
    if (kvin != qin) conv(kvin, Abf, SZX);
    expand(W + 1 * DD4, D, D);
    gemm_b(Abf, bb + 1 * (size_t)D * 4, kb, BT, 512, 512);
    expand(W + 2 * DD4, D, D);
    gemm_v(Abf, bb + 2 * (size_t)D * 4, vTb, BT, 512, 512);
    fused_attn_kernel<<<dim3(T / 64, NH, B), 256, 0, stream>>>(qb, kb, vTb, Abf, causal);
    expand(W + 3 * DD4, D, D);
    gemm_f(Abf, bb + 3 * (size_t)D * 4, outbuf, BT, 512, 512);
  };

  auto ff = [&](float* x, const float* W1, const float* b1, const float* mod,
                const float* W2, const float* b2, float* o) {
    conv(x, Abf, SZX);
    expand(W1, H, D);
    gemm_f(Abf, b1, hbuf, BT, 4 * H, 4 * D);
    modrelu_kernel<<<dim3(BT, H / 256), 256, 0, stream>>>(hbuf, mod);
    conv(hbuf, Abf, (size_t)BT * H * 4);
    expand(W2, D, H);
    gemm_f(Abf, b2, o, BT, 4 * D, 4 * H);
  };

  embed_rope_kernel<<<BT, 256, 0, stream>>>(src, emb, xsrc);
  embed_rope_kernel<<<BT, 256, 0, stream>>>(tgt, emb, xtgt);

  for (int l = 0; l < LE; ++l) {
    attention(xsrc, xsrc, enc_attn_W + (size_t)l * 16 * D * D,
              enc_attn_b + (size_t)l * 4 * D * 4, 0, tbuf);
    resid_qnorm_kernel<<<BT, 256, 0, stream>>>(
        xsrc, tbuf, enc_norm_g + (size_t)(l * 2 + 0) * D * 4,
        enc_norm_b + (size_t)(l * 2 + 0) * D * 4);
    ff(xsrc, enc_ff_W1 + (size_t)l * 4 * H * D, enc_ff_b1 + (size_t)l * H * 4,
       enc_ff_mod + (size_t)l * H, enc_ff_W2 + (size_t)l * 4 * D * H,
       enc_ff_b2 + (size_t)l * D * 4, tbuf);
    resid_qnorm_kernel<<<BT, 256, 0, stream>>>(
        xsrc, tbuf, enc_norm_g + (size_t)(l * 2 + 1) * D * 4,
        enc_norm_b + (size_t)(l * 2 + 1) * D * 4);
  }

  for (int l = 0; l < LD; ++l) {
    attention(xtgt, xtgt, dec_sa_W + (size_t)l * 16 * D * D,
              dec_sa_b + (size_t)l * 4 * D * 4, 1, tbuf);
    resid_qnorm_kernel<<<BT, 256, 0, stream>>>(
        xtgt, tbuf, dec_norm_g + (size_t)(l * 3 + 0) * D * 4,
        dec_norm_b + (size_t)(l * 3 + 0) * D * 4);
    attention(xtgt, xsrc, dec_ca_W + (size_t)l * 16 * D * D,
              dec_ca_b + (size_t)l * 4 * D * 4, 0, tbuf);
    resid_qnorm_kernel<<<BT, 256, 0, stream>>>(
        xtgt, tbuf, dec_norm_g + (size_t)(l * 3 + 1) * D * 4,
        dec_norm_b + (size_t)(l * 3 + 1) * D * 4);
    ff(xtgt, dec_ff_W1 + (size_t)l * 4 * H * D, dec_ff_b1 + (size_t)l * H * 4,
       dec_ff_mod + (size_t)l * H, dec_ff_W2 + (size_t)l * 4 * D * H,
       dec_ff_b2 + (size_t)l * D * 4, tbuf);
    resid_qnorm_kernel<<<BT, 256, 0, stream>>>(
        xtgt, tbuf, dec_norm_g + (size_t)(l * 3 + 2) * D * 4,
        dec_norm_b + (size_t)(l * 3 + 2) * D * 4);
  }

  to_real_kernel<<<BT, 256, 0, stream>>>(xtgt, realb);
  conv(realb, Abf, (size_t)BT * D);
  conv(fc_W, Wexp, (size_t)V * D);
  gemm_f(Abf, fc_b, out, BT, V, 256);
}

// Round 4
// 1337.231 us; speedup vs baseline: 24.5181x; 1.0583x over previous
//
#include <hip/hip_runtime.h>
#include <math.h>

#define B 4
#define T 512
#define D 256
#define H 1024
#define NH 8
#define V 32000
#define BT (B*T)
#define LE 2
#define LD 2
#define DIM 1024  // expanded width = 4*D

typedef __attribute__((ext_vector_type(8))) short s16x8;
typedef __attribute__((ext_vector_type(4))) float f32x4;
typedef __attribute__((address_space(3))) void lds_void;
typedef const __attribute__((address_space(1))) void g_void;

__device__ __forceinline__ ushort f2bf(float x) {
  uint u = __float_as_uint(x);
  return (ushort)((u + 0x7fffu + ((u >> 16) & 1u)) >> 16);
}
__device__ __forceinline__ float bf2f(ushort u) {
  return __uint_as_float(((uint)u) << 16);
}

// ---------------------------------------------------------------------------
// embed + rope fused: out f32 [BT, D, 4] + bf16 shadow
__global__ __launch_bounds__(256) void embed_rope_kernel(
    const int* __restrict__ ids, const float* __restrict__ emb,
    float* __restrict__ out, ushort* __restrict__ outbf) {
  int bt = blockIdx.x;
  int d  = threadIdx.x;
  int id = ids[bt];
  int t  = bt % T;
  size_t VD = (size_t)V * D;
  float scale = powf(10000.f, -(float)d / (float)D);
  float r = emb[(size_t)id * D + d];
  float i = emb[VD + (size_t)id * D + d] * scale;
  float j = emb[2 * VD + (size_t)id * D + d] * scale;
  float k = emb[3 * VD + (size_t)id * D + d] * scale;
  float n = sqrtf(r * r + i * i + j * j + k * k + 1e-6f);
  float ang;
  if (d < D / 2) {
    float inv = powf(10000.f, -(float)(2 * d) / (float)D);
    ang = sinf((float)t * inv);
  } else {
    float inv = powf(10000.f, -(float)(2 * (d - D / 2)) / (float)D);
    ang = cosf((float)t * inv);
  }
  float s = ang / n;
  size_t base = (size_t)bt * DIM + d * 4;
  float4 q = make_float4(r * s, i * s, j * s, k * s);
  *(float4*)(out + base) = q;
  *(ushort4*)(outbf + base) = make_ushort4(f2bf(q.x), f2bf(q.y), f2bf(q.z), f2bf(q.w));
}

// ---------------------------------------------------------------------------
__global__ __launch_bounds__(256) void f2bf_kernel(
    const float* __restrict__ in, ushort* __restrict__ out, int n4) {
  int i = blockIdx.x * 256 + threadIdx.x;
  if (i >= n4) return;
  float4 v = ((const float4*)in)[i];
  ((ushort4*)out)[i] = make_ushort4(f2bf(v.x), f2bf(v.y), f2bf(v.z), f2bf(v.w));
}

// ---------------------------------------------------------------------------
// expand quaternion weight W [4, Dout, Din] f32 -> Wt [4*Dout][4*Din] bf16 (B^T)
__global__ __launch_bounds__(64) void qexpand_kernel(
    const float* __restrict__ W, ushort* __restrict__ Wt, int Dout, int Din) {
  int d = blockIdx.x * 64 + threadIdx.x;
  int o = blockIdx.y;
  size_t P = (size_t)Dout * Din;
  float w0 = W[(size_t)o * Din + d];
  float w1 = W[P + (size_t)o * Din + d];
  float w2 = W[2 * P + (size_t)o * Din + d];
  float w3 = W[3 * P + (size_t)o * Din + d];
  int K4 = Din * 4;
  size_t rbase = (size_t)(o * 4) * K4 + d * 4;
  *(ushort4*)(Wt + rbase)          = make_ushort4(f2bf(w0), f2bf(-w1), f2bf(-w2), f2bf(-w3));
  *(ushort4*)(Wt + rbase + K4)     = make_ushort4(f2bf(w1), f2bf(w0),  f2bf(w3),  f2bf(-w2));
  *(ushort4*)(Wt + rbase + 2 * K4) = make_ushort4(f2bf(w2), f2bf(-w3), f2bf(w0),  f2bf(w1));
  *(ushort4*)(Wt + rbase + 3 * K4) = make_ushort4(f2bf(w3), f2bf(w2),  f2bf(-w1), f2bf(w0));
}

// ---------------------------------------------------------------------------
// C[M,N] = A[M,K]bf16 * Bt[N,K]bf16^T + bias
// OMODE 0: f32 out. OMODE 1: bf16 out. OMODE 3: QKV epilogue —
//   global col gc=colbase+col: [0,1024)->qo bf16, [1024,2048)->ko bf16,
//   [2048,3072)->vT transposed ([b*1024 + c]*T + t).
template <int OMODE>
__global__ __launch_bounds__(256) void gemm_bf16_kernel(
    const ushort* __restrict__ A, const ushort* __restrict__ Bt,
    const float* __restrict__ bias, void* __restrict__ Cv, int N, int K,
    ushort* __restrict__ qo, ushort* __restrict__ ko, ushort* __restrict__ vo,
    int colbase) {
  __shared__ ushort As[128 * 32];
  __shared__ ushort Bs[128 * 32];
  const int tid = threadIdx.x;
  const int w = tid >> 6, l = tid & 63;
  const int wm = w >> 1, wn = w & 1;
  const int m0 = blockIdx.y * 128, n0 = blockIdx.x * 128;
  const int lr = l & 15, lg = l >> 4;
  f32x4 acc[4][4] = {};
  for (int k0 = 0; k0 < K; k0 += 32) {
    if (k0) __syncthreads();
#pragma unroll
    for (int s = 0; s < 2; ++s) {
      int fb = (w * 2 + s) * 1024;
      int f = fb + l * 16;
      int row = f >> 6, cb = f & 63;
      const ushort* asrc = A + (size_t)(m0 + row) * K + k0 + (cb >> 1);
      const ushort* bsrc = Bt + (size_t)(n0 + row) * K + k0 + (cb >> 1);
      __builtin_amdgcn_global_load_lds((g_void*)asrc, (lds_void*)((char*)As + fb), 16, 0, 0);
      __builtin_amdgcn_global_load_lds((g_void*)bsrc, (lds_void*)((char*)Bs + fb), 16, 0, 0);
    }
    __syncthreads();
    s16x8 af[4], bfr[4];
#pragma unroll
    for (int mi = 0; mi < 4; ++mi)
      af[mi] = *(const s16x8*)(As + (wm * 64 + mi * 16 + lr) * 32 + lg * 8);
#pragma unroll
    for (int ni = 0; ni < 4; ++ni)
      bfr[ni] = *(const s16x8*)(Bs + (wn * 64 + ni * 16 + lr) * 32 + lg * 8);
#pragma unroll
    for (int mi = 0; mi < 4; ++mi)
#pragma unroll
      for (int ni = 0; ni < 4; ++ni)
        acc[mi][ni] = __builtin_amdgcn_mfma_f32_16x16x32_bf16(af[mi], bfr[ni], acc[mi][ni], 0, 0, 0);
  }
#pragma unroll
  for (int mi = 0; mi < 4; ++mi) {
#pragma unroll
    for (int ni = 0; ni < 4; ++ni) {
      int row = m0 + wm * 64 + mi * 16 + lg * 4;
      int col = n0 + wn * 64 + ni * 16 + lr;
      f32x4 v = acc[mi][ni];
      if constexpr (OMODE == 0) {
        float bv = bias ? bias[col] : 0.f;
        float* C = (float*)Cv;
#pragma unroll
        for (int r = 0; r < 4; ++r)
          C[(size_t)(row + r) * N + col] = v[r] + bv;
      } else if constexpr (OMODE == 1) {
        float bv = bias[col];
        ushort* C = (ushort*)Cv;
#pragma unroll
        for (int r = 0; r < 4; ++r)
          C[(size_t)(row + r) * N + col] = f2bf(v[r] + bv);
      } else {
        int gc = colbase + col;
        float bv = bias[gc];
        if (gc < 2048) {
          ushort* dst = (gc < DIM) ? qo : ko;
          int c = gc & (DIM - 1);
#pragma unroll
          for (int r = 0; r < 4; ++r)
            dst[(size_t)(row + r) * DIM + c] = f2bf(v[r] + bv);
        } else {
          int c = gc - 2048;  // head-concat dim 0..1023
          ushort4 o4 = make_ushort4(f2bf(v[0] + bv), f2bf(v[1] + bv),
                                    f2bf(v[2] + bv), f2bf(v[3] + bv));
          *(ushort4*)&vo[((size_t)((row >> 9) << 10) + c) * T + (row & 511)] = o4;
        }
      }
    }
  }
}

// ---------------------------------------------------------------------------
// fused flash attention, head-dim 128. grid (T/64, NH, B), 4 waves x 16 q-rows.
// qb,kb: [BT][1024] bf16 ; vT: [(b*NH+h)*128+d][T] bf16 ; outA: [BT][1024] bf16
__global__ __launch_bounds__(256) void fused_attn_kernel(
    const ushort* __restrict__ qb, const ushort* __restrict__ kb,
    const ushort* __restrict__ vT, ushort* __restrict__ outA, int causal) {
  __shared__ ushort Pst[4][1024];
  const int tid = threadIdx.x;
  const int wq = tid >> 6, l = tid & 63;
  const int lr = l & 15, lg = l >> 4;
  const int h = blockIdx.y, b = blockIdx.z;
  const int q0 = blockIdx.x * 64 + wq * 16;
  const size_t bT = (size_t)b * T;
  const int hc = h * 128;
  s16x8 qf[4];
#pragma unroll
  for (int ks = 0; ks < 4; ++ks)
    qf[ks] = *(const s16x8*)(qb + (bT + q0 + lr) * DIM + hc + ks * 32 + lg * 8);
  f32x4 O[8] = {};
  float m[4] = {-3e38f, -3e38f, -3e38f, -3e38f};
  float lac[4] = {0.f, 0.f, 0.f, 0.f};
  const int kend = causal ? ((q0 + 79) & ~63) : T;
  const ushort* vbase = vT + ((size_t)(b * NH + h) * 128) * T;
  for (int kv0 = 0; kv0 < kend; kv0 += 64) {
    f32x4 s[4] = {};
#pragma unroll
    for (int ks = 0; ks < 4; ++ks) {
      s16x8 kf[4];
#pragma unroll
      for (int ni = 0; ni < 4; ++ni)
        kf[ni] = *(const s16x8*)(kb + (bT + kv0 + ni * 16 + lr) * DIM + hc + ks * 32 + lg * 8);
#pragma unroll
      for (int ni = 0; ni < 4; ++ni)
        s[ni] = __builtin_amdgcn_mfma_f32_16x16x32_bf16(qf[ks], kf[ni], s[ni], 0, 0, 0);
    }
    const bool domask = causal && (kv0 + 63 > q0);
#pragma unroll
    for (int r = 0; r < 4; ++r) {
      const int qrow = q0 + lg * 4 + r;
      float mx = -3e38f;
#pragma unroll
      for (int ni = 0; ni < 4; ++ni) {
        float v = s[ni][r] * 0.08838834764831845f;
        if (domask && (kv0 + ni * 16 + lr > qrow)) v = -3e38f;
        s[ni][r] = v;
        mx = fmaxf(mx, v);
      }
#pragma unroll
      for (int dd = 1; dd < 16; dd <<= 1) mx = fmaxf(mx, __shfl_xor(mx, dd));
      float mn = fmaxf(m[r], mx);
      float alpha = __expf(m[r] - mn);
      m[r] = mn;
      float ps = 0.f;
#pragma unroll
      for (int ni = 0; ni < 4; ++ni) {
        float p = __expf(s[ni][r] - mn);
        s[ni][r] = p;
        ps += p;
      }
#pragma unroll
      for (int dd = 1; dd < 16; dd <<= 1) ps += __shfl_xor(ps, dd);
      lac[r] = lac[r] * alpha + ps;
#pragma unroll
      for (int dni = 0; dni < 8; ++dni) O[dni][r] *= alpha;
      const int qloc = lg * 4 + r;
      const int sw = (qloc & 7) << 3;
#pragma unroll
      for (int ni = 0; ni < 4; ++ni)
        Pst[wq][qloc * 64 + ((ni * 16 + lr) ^ sw)] = f2bf(s[ni][r]);
    }
    asm volatile("s_waitcnt lgkmcnt(0)" ::: "memory");
    __builtin_amdgcn_sched_barrier(0);
#pragma unroll
    for (int ks2 = 0; ks2 < 2; ++ks2) {
      s16x8 pa = *(const s16x8*)&Pst[wq][lr * 64 + ((ks2 * 32 + lg * 8) ^ ((lr & 7) << 3))];
#pragma unroll
      for (int dni = 0; dni < 8; ++dni) {
        s16x8 vf = *(const s16x8*)(vbase + (size_t)(dni * 16 + lr) * T + kv0 + ks2 * 32 + lg * 8);
        O[dni] = __builtin_amdgcn_mfma_f32_16x16x32_bf16(pa, vf, O[dni], 0, 0, 0);
      }
    }
  }
#pragma unroll
  for (int r = 0; r < 4; ++r) {
    float inv = 1.f / lac[r];
    const size_t row = bT + q0 + lg * 4 + r;
#pragma unroll
    for (int dni = 0; dni < 8; ++dni)
      outA[row * DIM + hc + dni * 16 + lr] = f2bf(O[dni][r] * inv);
  }
}

// ---------------------------------------------------------------------------
// x = g*((x+y)/|x+y|)+beta, dual-output f32 + bf16 shadow
__global__ __launch_bounds__(256) void resid_qnorm_kernel(
    float* __restrict__ x, const float* __restrict__ y,
    const float* __restrict__ g, const float* __restrict__ beta,
    ushort* __restrict__ xbf) {
  int n = blockIdx.x, d = threadIdx.x;
  size_t base = (size_t)n * DIM + d * 4;
  float4 xv = *(float4*)(x + base);
  float4 yv = *(const float4*)(y + base);
  float r = xv.x + yv.x, i = xv.y + yv.y, j = xv.z + yv.z, k = xv.w + yv.w;
  float invn = 1.f / sqrtf(r * r + i * i + j * j + k * k + 1e-6f);
  float4 gv = ((const float4*)g)[d];
  float4 bv = ((const float4*)beta)[d];
  float4 res;
  res.x = gv.x * (r * invn) + bv.x;
  res.y = gv.y * (i * invn) + bv.y;
  res.z = gv.z * (j * invn) + bv.z;
  res.w = gv.w * (k * invn) + bv.w;
  *(float4*)(x + base) = res;
  *(ushort4*)(xbf + base) = make_ushort4(f2bf(res.x), f2bf(res.y), f2bf(res.z), f2bf(res.w));
}

// ---------------------------------------------------------------------------
// modrelu in place on bf16 [BT, H, 4]
__global__ __launch_bounds__(256) void modrelu_kernel(
    ushort* __restrict__ x, const float* __restrict__ bias) {
  int n = blockIdx.x;
  int f = blockIdx.y * 256 + threadIdx.x;
  size_t base = (size_t)n * (H * 4) + f * 4;
  ushort4 u = *(ushort4*)(x + base);
  float a = bf2f(u.x), b2 = bf2f(u.y), c = bf2f(u.z), d = bf2f(u.w);
  float norm = sqrtf(a * a + b2 * b2 + c * c + d * d);
  float scale = fmaxf(norm + bias[f], 0.f) / (norm + 1e-6f);
  *(ushort4*)(x + base) = make_ushort4(f2bf(a * scale), f2bf(b2 * scale),
                                       f2bf(c * scale), f2bf(d * scale));
}

// ---------------------------------------------------------------------------
__global__ __launch_bounds__(256) void to_real_kernel(
    const float* __restrict__ x, ushort* __restrict__ realbf) {
  int n = blockIdx.x, d = threadIdx.x;
  float4 v = ((const float4*)x)[(size_t)n * D + d];
  realbf[(size_t)n * D + d] = f2bf(sqrtf(v.x * v.x + v.y * v.y + v.z * v.z + v.w * v.w));
}

// ---------------------------------------------------------------------------
extern "C" void kernel_launch(void* const* d_in, const int* in_sizes, int n_in,
                              void* d_out, int out_size, void* d_ws, size_t ws_size,
                              hipStream_t stream) {
  const int*   src        = (const int*)d_in[0];
  const int*   tgt        = (const int*)d_in[1];
  const float* emb        = (const float*)d_in[3];
  const float* enc_attn_W = (const float*)d_in[4];
  const float* enc_attn_b = (const float*)d_in[5];
  const float* enc_norm_g = (const float*)d_in[6];
  const float* enc_norm_b = (const float*)d_in[7];
  const float* enc_ff_W1  = (const float*)d_in[8];
  const float* enc_ff_b1  = (const float*)d_in[9];
  const float* enc_ff_mod = (const float*)d_in[10];
  const float* enc_ff_W2  = (const float*)d_in[11];
  const float* enc_ff_b2  = (const float*)d_in[12];
  const float* dec_sa_W   = (const float*)d_in[13];
  const float* dec_sa_b   = (const float*)d_in[14];
  const float* dec_ca_W   = (const float*)d_in[15];
  const float* dec_ca_b   = (const float*)d_in[16];
  const float* dec_norm_g = (const float*)d_in[17];
  const float* dec_norm_b = (const float*)d_in[18];
  const float* dec_ff_W1  = (const float*)d_in[19];
  const float* dec_ff_b1  = (const float*)d_in[20];
  const float* dec_ff_mod = (const float*)d_in[21];
  const float* dec_ff_W2  = (const float*)d_in[22];
  const float* dec_ff_b2  = (const float*)d_in[23];
  const float* fc_W       = (const float*)d_in[24];
  const float* fc_b       = (const float*)d_in[25];
  float* out = (float*)d_out;

  const size_t SZX = (size_t)BT * DIM;  // 2,097,152
  float* ws    = (float*)d_ws;
  float* xsrc  = ws;
  float* xtgt  = xsrc + SZX;
  float* tbuf  = xtgt + SZX;
  ushort* xbf_src = (ushort*)(tbuf + SZX);
  ushort* xbf_tgt = xbf_src + SZX;
  ushort* aobf    = xbf_tgt + SZX;
  ushort* qb      = aobf + SZX;
  ushort* kb      = qb + SZX;
  ushort* vTb     = kb + SZX;
  ushort* hbf     = vTb + SZX;                    // BT*4096
  ushort* realbf  = hbf + (size_t)BT * H * 4;     // BT*256
  ushort* Wexp    = realbf + (size_t)BT * D;      // up to V*D

  const size_t WSTEP = (size_t)DIM * DIM;  // 1,048,576 elems per expanded proj

  auto expand = [&](const float* Wq, ushort* dst, int Dout, int Din) {
    qexpand_kernel<<<dim3(Din / 64, Dout), 64, 0, stream>>>(Wq, dst, Dout, Din);
  };
  auto gemm_f = [&](const ushort* Ab, const ushort* Bt, const float* bias,
                    float* Cc, int M, int N, int K) {
    gemm_bf16_kernel<0><<<dim3(N / 128, M / 128), 256, 0, stream>>>(
        Ab, Bt, bias, Cc, N, K, nullptr, nullptr, nullptr, 0);
  };
  auto gemm_b = [&](const ushort* Ab, const ushort* Bt, const float* bias,
                    ushort* Cc, int M, int N, int K) {
    gemm_bf16_kernel<1><<<dim3(N / 128, M / 128), 256, 0, stream>>>(
        Ab, Bt, bias, Cc, N, K, nullptr, nullptr, nullptr, 0);
  };
  auto gemm_qkv = [&](const ushort* Ab, const ushort* Bt, const float* bias,
                      int M, int N, int colbase) {
    gemm_bf16_kernel<3><<<dim3(N / 128, M / 128), 256, 0, stream>>>(
        Ab, Bt, bias, nullptr, N, DIM, qb, kb, vTb, colbase);
  };

  const size_t DD4 = (size_t)4 * D * D;
  // qbf_in: bf16 of query-side input; kvbf_in: bf16 of kv-side input
  auto attention = [&](const ushort* qbf_in, const ushort* kvbf_in, const float* W,
                       const float* bb, int causal, float* outbuf) {
    expand(W + 0 * DD4, Wexp, D, D);
    expand(W + 1 * DD4, Wexp + WSTEP, D, D);
    expand(W + 2 * DD4, Wexp + 2 * WSTEP, D, D);
    if (qbf_in == kvbf_in) {
      gemm_qkv(qbf_in, Wexp, bb, BT, 3 * DIM, 0);
    } else {
      gemm_qkv(qbf_in, Wexp, bb, BT, DIM, 0);
      gemm_qkv(kvbf_in, Wexp + WSTEP, bb, BT, 2 * DIM, DIM);
    }
    fused_attn_kernel<<<dim3(T / 64, NH, B), 256, 0, stream>>>(qb, kb, vTb, aobf, causal);
    expand(W + 3 * DD4, Wexp, D, D);
    gemm_f(aobf, Wexp, bb + 3 * (size_t)D * 4, outbuf, BT, DIM, DIM);
  };

  auto ff = [&](float* x, const ushort* xbf, ushort* xbf_out, const float* W1,
                const float* b1, const float* mod, const float* W2, const float* b2,
                float* o) {
    expand(W1, Wexp, H, D);
    gemm_b(xbf, Wexp, b1, hbf, BT, 4 * H, DIM);
    modrelu_kernel<<<dim3(BT, H / 256), 256, 0, stream>>>(hbf, mod);
    expand(W2, Wexp, D, H);
    gemm_f(hbf, Wexp, b2, o, BT, DIM, 4 * H);
  };

  embed_rope_kernel<<<BT, 256, 0, stream>>>(src, emb, xsrc, xbf_src);
  embed_rope_kernel<<<BT, 256, 0, stream>>>(tgt, emb, xtgt, xbf_tgt);

  for (int l = 0; l < LE; ++l) {
    attention(xbf_src, xbf_src, enc_attn_W + (size_t)l * 16 * D * D,
              enc_attn_b + (size_t)l * 4 * D * 4, 0, tbuf);
    resid_qnorm_kernel<<<BT, 256, 0, stream>>>(
        xsrc, tbuf, enc_norm_g + (size_t)(l * 2 + 0) * DIM,
        enc_norm_b + (size_t)(l * 2 + 0) * DIM, xbf_src);
    ff(xsrc, xbf_src, xbf_src, enc_ff_W1 + (size_t)l * 4 * H * D,
       enc_ff_b1 + (size_t)l * H * 4, enc_ff_mod + (size_t)l * H,
       enc_ff_W2 + (size_t)l * 4 * D * H, enc_ff_b2 + (size_t)l * DIM, tbuf);
    resid_qnorm_kernel<<<BT, 256, 0, stream>>>(
        xsrc, tbuf, enc_norm_g + (size_t)(l * 2 + 1) * DIM,
        enc_norm_b + (size_t)(l * 2 + 1) * DIM, xbf_src);
  }

  for (int l = 0; l < LD; ++l) {
    attention(xbf_tgt, xbf_tgt, dec_sa_W + (size_t)l * 16 * D * D,
              dec_sa_b + (size_t)l * 4 * D * 4, 1, tbuf);
    resid_qnorm_kernel<<<BT, 256, 0, stream>>>(
        xtgt, tbuf, dec_norm_g + (size_t)(l * 3 + 0) * DIM,
        dec_norm_b + (size_t)(l * 3 + 0) * DIM, xbf_tgt);
    attention(xbf_tgt, xbf_src, dec_ca_W + (size_t)l * 16 * D * D,
              dec_ca_b + (size_t)l * 4 * D * 4, 0, tbuf);
    resid_qnorm_kernel<<<BT, 256, 0, stream>>>(
        xtgt, tbuf, dec_norm_g + (size_t)(l * 3 + 1) * DIM,
        dec_norm_b + (size_t)(l * 3 + 1) * DIM, xbf_tgt);
    ff(xtgt, xbf_tgt, xbf_tgt, dec_ff_W1 + (size_t)l * 4 * H * D,
       dec_ff_b1 + (size_t)l * H * 4, dec_ff_mod + (size_t)l * H,
       dec_ff_W2 + (size_t)l * 4 * D * H, dec_ff_b2 + (size_t)l * DIM, tbuf);
    resid_qnorm_kernel<<<BT, 256, 0, stream>>>(
        xtgt, tbuf, dec_norm_g + (size_t)(l * 3 + 2) * DIM,
        dec_norm_b + (size_t)(l * 3 + 2) * DIM, xbf_tgt);
  }

  to_real_kernel<<<BT, 256, 0, stream>>>(xtgt, realbf);
  f2bf_kernel<<<((V * D / 4) + 255) / 256, 256, 0, stream>>>(fc_W, Wexp, V * D / 4);
  gemm_f(realbf, Wexp, fc_b, out, BT, V, 256);
}

// Round 5
// 1262.618 us; speedup vs baseline: 25.9670x; 1.0591x over previous
//
#include <hip/hip_runtime.h>
#include <math.h>

#define B 4
#define T 512
#define D 256
#define H 1024
#define NH 8
#define V 32000
#define BT (B*T)
#define LE 2
#define LD 2
#define DIM 1024  // expanded width = 4*D

typedef __attribute__((ext_vector_type(8))) short s16x8;
typedef __attribute__((ext_vector_type(4))) float f32x4;
typedef __attribute__((address_space(3))) void lds_void;
typedef const __attribute__((address_space(1))) void g_void;

__device__ __forceinline__ ushort f2bf(float x) {
  uint u = __float_as_uint(x);
  return (ushort)((u + 0x7fffu + ((u >> 16) & 1u)) >> 16);
}
__device__ __forceinline__ float bf2f(ushort u) {
  return __uint_as_float(((uint)u) << 16);
}

// ---------------------------------------------------------------------------
// embed + rope fused for BOTH src and tgt: grid 2*BT
__global__ __launch_bounds__(256) void embed_rope_kernel(
    const int* __restrict__ src, const int* __restrict__ tgt,
    const float* __restrict__ emb,
    float* __restrict__ osrc, ushort* __restrict__ osrcbf,
    float* __restrict__ otgt, ushort* __restrict__ otgtbf) {
  int g = blockIdx.x;
  int isTgt = g >= BT;
  int bt = isTgt ? g - BT : g;
  int d  = threadIdx.x;
  int id = isTgt ? tgt[bt] : src[bt];
  float* out = isTgt ? otgt : osrc;
  ushort* outbf = isTgt ? otgtbf : osrcbf;
  int t  = bt % T;
  size_t VD = (size_t)V * D;
  float scale = powf(10000.f, -(float)d / (float)D);
  float r = emb[(size_t)id * D + d];
  float i = emb[VD + (size_t)id * D + d] * scale;
  float j = emb[2 * VD + (size_t)id * D + d] * scale;
  float k = emb[3 * VD + (size_t)id * D + d] * scale;
  float n = sqrtf(r * r + i * i + j * j + k * k + 1e-6f);
  float ang;
  if (d < D / 2) {
    float inv = powf(10000.f, -(float)(2 * d) / (float)D);
    ang = sinf((float)t * inv);
  } else {
    float inv = powf(10000.f, -(float)(2 * (d - D / 2)) / (float)D);
    ang = cosf((float)t * inv);
  }
  float s = ang / n;
  size_t base = (size_t)bt * DIM + d * 4;
  float4 q = make_float4(r * s, i * s, j * s, k * s);
  *(float4*)(out + base) = q;
  *(ushort4*)(outbf + base) = make_ushort4(f2bf(q.x), f2bf(q.y), f2bf(q.z), f2bf(q.w));
}

// ---------------------------------------------------------------------------
// ONE launch: expand all attention + FF quaternion weights to bf16 B^T form,
// and convert fc_W to bf16.
// Work layout (one thread per (proj,o,d) quaternion entry, or 4 fc elems):
//   [0, A_CNT): 6 attn units x 4 proj x 256 x 256
//   [A_CNT, A_CNT+F_CNT): 4 FF layers x (W1 1024x256 + W2 256x1024)
//   [.., +FC_CNT): fc_W V*D/4
#define A_CNT  1572864
#define F_CNT  2097152
#define FC_CNT 2048000
#define MEGA_TOT (A_CNT + F_CNT + FC_CNT)
#define WSTEP  1048576   // DIM*DIM elems
#define FFW    4194304   // 4H*DIM elems

__device__ __forceinline__ void qexpand_write(
    const float* __restrict__ src, ushort* __restrict__ dst,
    int o, int d, int Din, int P) {
  float w0 = src[(size_t)o * Din + d];
  float w1 = src[P + (size_t)o * Din + d];
  float w2 = src[2 * (size_t)P + (size_t)o * Din + d];
  float w3 = src[3 * (size_t)P + (size_t)o * Din + d];
  int K4 = Din * 4;
  size_t rbase = (size_t)(o * 4) * K4 + d * 4;
  *(ushort4*)(dst + rbase)          = make_ushort4(f2bf(w0), f2bf(-w1), f2bf(-w2), f2bf(-w3));
  *(ushort4*)(dst + rbase + K4)     = make_ushort4(f2bf(w1), f2bf(w0),  f2bf(w3),  f2bf(-w2));
  *(ushort4*)(dst + rbase + 2 * K4) = make_ushort4(f2bf(w2), f2bf(-w3), f2bf(w0),  f2bf(w1));
  *(ushort4*)(dst + rbase + 3 * K4) = make_ushort4(f2bf(w3), f2bf(w2),  f2bf(-w1), f2bf(w0));
}

__global__ __launch_bounds__(256) void mega_expand_kernel(
    const float* __restrict__ encA, const float* __restrict__ decSA,
    const float* __restrict__ decCA,
    const float* __restrict__ eW1, const float* __restrict__ eW2,
    const float* __restrict__ dW1, const float* __restrict__ dW2,
    const float* __restrict__ fcW,
    ushort* __restrict__ WA, ushort* __restrict__ WF, ushort* __restrict__ Wfc) {
  int gid = blockIdx.x * 256 + threadIdx.x;
  if (gid < A_CNT) {
    int u = gid >> 18;            // attn unit 0..5
    int p = (gid >> 16) & 3;      // projection
    int rem = gid & 65535;
    int o = rem >> 8, d = rem & 255;
    const float* base = (u < 2) ? encA + (size_t)u * 1048576
                      : (u < 4) ? decSA + (size_t)(u - 2) * 1048576
                                : decCA + (size_t)(u - 4) * 1048576;
    qexpand_write(base + (size_t)p * 262144,
                  WA + ((size_t)u * 4 + p) * WSTEP, o, d, 256, 65536);
  } else if (gid < A_CNT + F_CNT) {
    int idx = gid - A_CNT;
    int layer = idx >> 19;        // 0,1 enc; 2,3 dec
    int w12 = (idx >> 18) & 1;
    int rem = idx & 262143;
    const float* w1b = (layer < 2) ? eW1 + (size_t)layer * 1048576
                                   : dW1 + (size_t)(layer - 2) * 1048576;
    const float* w2b = (layer < 2) ? eW2 + (size_t)layer * 1048576
                                   : dW2 + (size_t)(layer - 2) * 1048576;
    ushort* dst = WF + (size_t)layer * 2 * FFW + (size_t)w12 * FFW;
    if (w12 == 0) {
      int o = rem >> 8, d = rem & 255;
      qexpand_write(w1b, dst, o, d, 256, 262144);
    } else {
      int o = rem >> 10, d = rem & 1023;
      qexpand_write(w2b, dst, o, d, 1024, 262144);
    }
  } else {
    int idx = gid - A_CNT - F_CNT;
    if (idx < FC_CNT) {
      float4 v = ((const float4*)fcW)[idx];
      ((ushort4*)Wfc)[idx] = make_ushort4(f2bf(v.x), f2bf(v.y), f2bf(v.z), f2bf(v.w));
    }
  }
}

// ---------------------------------------------------------------------------
// C[M,N] = A[M,K]bf16 * Bt[N,K]bf16^T + bias
// TM: 128 (4 waves 2x2, acc 4x4) or 64 (4 waves 1x4, acc 4x2).
// OMODE 0: f32 out. OMODE 1: bf16 out. OMODE 3: QKV epilogue
//   (gc<1024 -> qo, <2048 -> ko, else vo transposed [b*1024+c][T]).
template <int OMODE, int TM>
__global__ __launch_bounds__(256) void gemm_bf16_kernel(
    const ushort* __restrict__ A, const ushort* __restrict__ Bt,
    const float* __restrict__ bias, void* __restrict__ Cv, int N, int K,
    ushort* __restrict__ qo, ushort* __restrict__ ko, ushort* __restrict__ vo,
    int colbase) {
  __shared__ ushort As[TM * 32];
  __shared__ ushort Bs[128 * 32];
  const int tid = threadIdx.x;
  const int w = tid >> 6, l = tid & 63;
  const int m0 = blockIdx.y * TM, n0 = blockIdx.x * 128;
  const int lr = l & 15, lg = l >> 4;
  constexpr int NR = (TM == 128) ? 4 : 2;
  const int wm = (TM == 128) ? (w >> 1) : 0;
  const int wn = (TM == 128) ? (w & 1) : w;
  const int wcol = wn * (NR * 16);
  f32x4 acc[4][NR] = {};
  for (int k0 = 0; k0 < K; k0 += 32) {
    if (k0) __syncthreads();
    // stage A (TM*64 bytes) + B (8192 bytes); each 1024B seg = 16 rows
    if constexpr (TM == 128) {
#pragma unroll
      for (int s = 0; s < 2; ++s) {
        int fb = (w * 2 + s) * 1024;
        int f = fb + l * 16;
        int row = f >> 6, cb = f & 63;
        __builtin_amdgcn_global_load_lds(
            (g_void*)(A + (size_t)(m0 + row) * K + k0 + (cb >> 1)),
            (lds_void*)((char*)As + fb), 16, 0, 0);
      }
    } else {
      int fb = w * 1024;
      int f = fb + l * 16;
      int row = f >> 6, cb = f & 63;
      __builtin_amdgcn_global_load_lds(
          (g_void*)(A + (size_t)(m0 + row) * K + k0 + (cb >> 1)),
          (lds_void*)((char*)As + fb), 16, 0, 0);
    }
#pragma unroll
    for (int s = 0; s < 2; ++s) {
      int fb = (w * 2 + s) * 1024;
      int f = fb + l * 16;
      int row = f >> 6, cb = f & 63;
      __builtin_amdgcn_global_load_lds(
          (g_void*)(Bt + (size_t)(n0 + row) * K + k0 + (cb >> 1)),
          (lds_void*)((char*)Bs + fb), 16, 0, 0);
    }
    __syncthreads();
    s16x8 af[4], bfr[NR];
#pragma unroll
    for (int mi = 0; mi < 4; ++mi)
      af[mi] = *(const s16x8*)(As + (wm * 64 + mi * 16 + lr) * 32 + lg * 8);
#pragma unroll
    for (int ni = 0; ni < NR; ++ni)
      bfr[ni] = *(const s16x8*)(Bs + (wcol + ni * 16 + lr) * 32 + lg * 8);
#pragma unroll
    for (int mi = 0; mi < 4; ++mi)
#pragma unroll
      for (int ni = 0; ni < NR; ++ni)
        acc[mi][ni] = __builtin_amdgcn_mfma_f32_16x16x32_bf16(af[mi], bfr[ni], acc[mi][ni], 0, 0, 0);
  }
#pragma unroll
  for (int mi = 0; mi < 4; ++mi) {
#pragma unroll
    for (int ni = 0; ni < NR; ++ni) {
      int row = m0 + wm * 64 + mi * 16 + lg * 4;
      int col = n0 + wcol + ni * 16 + lr;
      f32x4 v = acc[mi][ni];
      if constexpr (OMODE == 0) {
        float bv = bias ? bias[col] : 0.f;
        float* C = (float*)Cv;
#pragma unroll
        for (int r = 0; r < 4; ++r)
          C[(size_t)(row + r) * N + col] = v[r] + bv;
      } else if constexpr (OMODE == 1) {
        float bv = bias[col];
        ushort* C = (ushort*)Cv;
#pragma unroll
        for (int r = 0; r < 4; ++r)
          C[(size_t)(row + r) * N + col] = f2bf(v[r] + bv);
      } else {
        int gc = colbase + col;
        float bv = bias[gc];
        if (gc < 2048) {
          ushort* dst = (gc < DIM) ? qo : ko;
          int c = gc & (DIM - 1);
#pragma unroll
          for (int r = 0; r < 4; ++r)
            dst[(size_t)(row + r) * DIM + c] = f2bf(v[r] + bv);
        } else {
          int c = gc - 2048;
          ushort4 o4 = make_ushort4(f2bf(v[0] + bv), f2bf(v[1] + bv),
                                    f2bf(v[2] + bv), f2bf(v[3] + bv));
          *(ushort4*)&vo[((size_t)((row >> 9) << 10) + c) * T + (row & 511)] = o4;
        }
      }
    }
  }
}

// ---------------------------------------------------------------------------
// fused flash attention, head-dim 128. grid (T/64, NH, B), 4 waves x 16 q-rows.
__global__ __launch_bounds__(256) void fused_attn_kernel(
    const ushort* __restrict__ qb, const ushort* __restrict__ kb,
    const ushort* __restrict__ vT, ushort* __restrict__ outA, int causal) {
  __shared__ ushort Pst[4][1024];
  const int tid = threadIdx.x;
  const int wq = tid >> 6, l = tid & 63;
  const int lr = l & 15, lg = l >> 4;
  const int h = blockIdx.y, b = blockIdx.z;
  const int q0 = blockIdx.x * 64 + wq * 16;
  const size_t bT = (size_t)b * T;
  const int hc = h * 128;
  s16x8 qf[4];
#pragma unroll
  for (int ks = 0; ks < 4; ++ks)
    qf[ks] = *(const s16x8*)(qb + (bT + q0 + lr) * DIM + hc + ks * 32 + lg * 8);
  f32x4 O[8] = {};
  float m[4] = {-3e38f, -3e38f, -3e38f, -3e38f};
  float lac[4] = {0.f, 0.f, 0.f, 0.f};
  const int kend = causal ? ((q0 + 79) & ~63) : T;
  const ushort* vbase = vT + ((size_t)(b * NH + h) * 128) * T;
  for (int kv0 = 0; kv0 < kend; kv0 += 64) {
    f32x4 s[4] = {};
#pragma unroll
    for (int ks = 0; ks < 4; ++ks) {
      s16x8 kf[4];
#pragma unroll
      for (int ni = 0; ni < 4; ++ni)
        kf[ni] = *(const s16x8*)(kb + (bT + kv0 + ni * 16 + lr) * DIM + hc + ks * 32 + lg * 8);
#pragma unroll
      for (int ni = 0; ni < 4; ++ni)
        s[ni] = __builtin_amdgcn_mfma_f32_16x16x32_bf16(qf[ks], kf[ni], s[ni], 0, 0, 0);
    }
    const bool domask = causal && (kv0 + 63 > q0);
#pragma unroll
    for (int r = 0; r < 4; ++r) {
      const int qrow = q0 + lg * 4 + r;
      float mx = -3e38f;
#pragma unroll
      for (int ni = 0; ni < 4; ++ni) {
        float v = s[ni][r] * 0.08838834764831845f;
        if (domask && (kv0 + ni * 16 + lr > qrow)) v = -3e38f;
        s[ni][r] = v;
        mx = fmaxf(mx, v);
      }
#pragma unroll
      for (int dd = 1; dd < 16; dd <<= 1) mx = fmaxf(mx, __shfl_xor(mx, dd));
      float mn = fmaxf(m[r], mx);
      float alpha = __expf(m[r] - mn);
      m[r] = mn;
      float ps = 0.f;
#pragma unroll
      for (int ni = 0; ni < 4; ++ni) {
        float p = __expf(s[ni][r] - mn);
        s[ni][r] = p;
        ps += p;
      }
#pragma unroll
      for (int dd = 1; dd < 16; dd <<= 1) ps += __shfl_xor(ps, dd);
      lac[r] = lac[r] * alpha + ps;
#pragma unroll
      for (int dni = 0; dni < 8; ++dni) O[dni][r] *= alpha;
      const int qloc = lg * 4 + r;
      const int sw = (qloc & 7) << 3;
#pragma unroll
      for (int ni = 0; ni < 4; ++ni)
        Pst[wq][qloc * 64 + ((ni * 16 + lr) ^ sw)] = f2bf(s[ni][r]);
    }
    asm volatile("s_waitcnt lgkmcnt(0)" ::: "memory");
    __builtin_amdgcn_sched_barrier(0);
#pragma unroll
    for (int ks2 = 0; ks2 < 2; ++ks2) {
      s16x8 pa = *(const s16x8*)&Pst[wq][lr * 64 + ((ks2 * 32 + lg * 8) ^ ((lr & 7) << 3))];
#pragma unroll
      for (int dni = 0; dni < 8; ++dni) {
        s16x8 vf = *(const s16x8*)(vbase + (size_t)(dni * 16 + lr) * T + kv0 + ks2 * 32 + lg * 8);
        O[dni] = __builtin_amdgcn_mfma_f32_16x16x32_bf16(pa, vf, O[dni], 0, 0, 0);
      }
    }
  }
#pragma unroll
  for (int r = 0; r < 4; ++r) {
    float inv = 1.f / lac[r];
    const size_t row = bT + q0 + lg * 4 + r;
#pragma unroll
    for (int dni = 0; dni < 8; ++dni)
      outA[row * DIM + hc + dni * 16 + lr] = f2bf(O[dni][r] * inv);
  }
}

// ---------------------------------------------------------------------------
__global__ __launch_bounds__(256) void resid_qnorm_kernel(
    float* __restrict__ x, const float* __restrict__ y,
    const float* __restrict__ g, const float* __restrict__ beta,
    ushort* __restrict__ xbf) {
  int n = blockIdx.x, d = threadIdx.x;
  size_t base = (size_t)n * DIM + d * 4;
  float4 xv = *(float4*)(x + base);
  float4 yv = *(const float4*)(y + base);
  float r = xv.x + yv.x, i = xv.y + yv.y, j = xv.z + yv.z, k = xv.w + yv.w;
  float invn = 1.f / sqrtf(r * r + i * i + j * j + k * k + 1e-6f);
  float4 gv = ((const float4*)g)[d];
  float4 bv = ((const float4*)beta)[d];
  float4 res;
  res.x = gv.x * (r * invn) + bv.x;
  res.y = gv.y * (i * invn) + bv.y;
  res.z = gv.z * (j * invn) + bv.z;
  res.w = gv.w * (k * invn) + bv.w;
  *(float4*)(x + base) = res;
  *(ushort4*)(xbf + base) = make_ushort4(f2bf(res.x), f2bf(res.y), f2bf(res.z), f2bf(res.w));
}

// ---------------------------------------------------------------------------
__global__ __launch_bounds__(256) void modrelu_kernel(
    ushort* __restrict__ x, const float* __restrict__ bias) {
  int n = blockIdx.x;
  int f = blockIdx.y * 256 + threadIdx.x;
  size_t base = (size_t)n * (H * 4) + f * 4;
  ushort4 u = *(ushort4*)(x + base);
  float a = bf2f(u.x), b2 = bf2f(u.y), c = bf2f(u.z), d = bf2f(u.w);
  float norm = sqrtf(a * a + b2 * b2 + c * c + d * d);
  float scale = fmaxf(norm + bias[f], 0.f) / (norm + 1e-6f);
  *(ushort4*)(x + base) = make_ushort4(f2bf(a * scale), f2bf(b2 * scale),
                                       f2bf(c * scale), f2bf(d * scale));
}

// ---------------------------------------------------------------------------
__global__ __launch_bounds__(256) void to_real_kernel(
    const float* __restrict__ x, ushort* __restrict__ realbf) {
  int n = blockIdx.x, d = threadIdx.x;
  float4 v = ((const float4*)x)[(size_t)n * D + d];
  realbf[(size_t)n * D + d] = f2bf(sqrtf(v.x * v.x + v.y * v.y + v.z * v.z + v.w * v.w));
}

// ---------------------------------------------------------------------------
extern "C" void kernel_launch(void* const* d_in, const int* in_sizes, int n_in,
                              void* d_out, int out_size, void* d_ws, size_t ws_size,
                              hipStream_t stream) {
  const int*   src        = (const int*)d_in[0];
  const int*   tgt        = (const int*)d_in[1];
  const float* emb        = (const float*)d_in[3];
  const float* enc_attn_W = (const float*)d_in[4];
  const float* enc_attn_b = (const float*)d_in[5];
  const float* enc_norm_g = (const float*)d_in[6];
  const float* enc_norm_b = (const float*)d_in[7];
  const float* enc_ff_W1  = (const float*)d_in[8];
  const float* enc_ff_b1  = (const float*)d_in[9];
  const float* enc_ff_mod = (const float*)d_in[10];
  const float* enc_ff_W2  = (const float*)d_in[11];
  const float* enc_ff_b2  = (const float*)d_in[12];
  const float* dec_sa_W   = (const float*)d_in[13];
  const float* dec_sa_b   = (const float*)d_in[14];
  const float* dec_ca_W   = (const float*)d_in[15];
  const float* dec_ca_b   = (const float*)d_in[16];
  const float* dec_norm_g = (const float*)d_in[17];
  const float* dec_norm_b = (const float*)d_in[18];
  const float* dec_ff_W1  = (const float*)d_in[19];
  const float* dec_ff_b1  = (const float*)d_in[20];
  const float* dec_ff_mod = (const float*)d_in[21];
  const float* dec_ff_W2  = (const float*)d_in[22];
  const float* dec_ff_b2  = (const float*)d_in[23];
  const float* fc_W       = (const float*)d_in[24];
  const float* fc_b       = (const float*)d_in[25];
  float* out = (float*)d_out;

  const size_t SZX = (size_t)BT * DIM;  // 2,097,152
  float* ws    = (float*)d_ws;
  float* xsrc  = ws;
  float* xtgt  = xsrc + SZX;
  float* tbuf  = xtgt + SZX;
  ushort* xbf_src = (ushort*)(tbuf + SZX);
  ushort* xbf_tgt = xbf_src + SZX;
  ushort* aobf    = xbf_tgt + SZX;
  ushort* qb      = aobf + SZX;
  ushort* kb      = qb + SZX;
  ushort* vTb     = kb + SZX;
  ushort* hbf     = vTb + SZX;                    // BT*4096
  ushort* realbf  = hbf + (size_t)BT * H * 4;     // BT*256
  ushort* WA      = realbf + (size_t)BT * D;      // 6 attn units * 4*WSTEP
  ushort* WF      = WA + (size_t)6 * 4 * WSTEP;   // 4 FF layers * 2*FFW
  ushort* Wfc     = WF + (size_t)4 * 2 * FFW;     // V*D

  // ---- one launch: all weight expansion + fc conversion
  mega_expand_kernel<<<(MEGA_TOT + 255) / 256, 256, 0, stream>>>(
      enc_attn_W, dec_sa_W, dec_ca_W,
      enc_ff_W1, enc_ff_W2, dec_ff_W1, dec_ff_W2, fc_W, WA, WF, Wfc);

  auto g128_f = [&](const ushort* Ab, const ushort* Bt, const float* bias,
                    float* Cc, int M, int N, int K) {
    gemm_bf16_kernel<0, 128><<<dim3(N / 128, M / 128), 256, 0, stream>>>(
        Ab, Bt, bias, Cc, N, K, nullptr, nullptr, nullptr, 0);
  };
  auto g64_f = [&](const ushort* Ab, const ushort* Bt, const float* bias,
                   float* Cc, int M, int N, int K) {
    gemm_bf16_kernel<0, 64><<<dim3(N / 128, M / 64), 256, 0, stream>>>(
        Ab, Bt, bias, Cc, N, K, nullptr, nullptr, nullptr, 0);
  };
  auto g128_b = [&](const ushort* Ab, const ushort* Bt, const float* bias,
                    ushort* Cc, int M, int N, int K) {
    gemm_bf16_kernel<1, 128><<<dim3(N / 128, M / 128), 256, 0, stream>>>(
        Ab, Bt, bias, Cc, N, K, nullptr, nullptr, nullptr, 0);
  };
  auto g128_qkv = [&](const ushort* Ab, const ushort* Bt, const float* bias,
                      int M, int N, int colbase) {
    gemm_bf16_kernel<3, 128><<<dim3(N / 128, M / 128), 256, 0, stream>>>(
        Ab, Bt, bias, nullptr, N, DIM, qb, kb, vTb, colbase);
  };
  auto g64_qkv = [&](const ushort* Ab, const ushort* Bt, const float* bias,
                     int M, int N, int colbase) {
    gemm_bf16_kernel<3, 64><<<dim3(N / 128, M / 64), 256, 0, stream>>>(
        Ab, Bt, bias, nullptr, N, DIM, qb, kb, vTb, colbase);
  };

  // unit: 0,1 enc; 2,3 dec_sa; 4,5 dec_ca
  auto attention = [&](const ushort* qbf_in, const ushort* kvbf_in, int unit,
                       const float* bb, int causal, float* outbuf) {
    const ushort* Wu = WA + (size_t)unit * 4 * WSTEP;
    if (qbf_in == kvbf_in) {
      g128_qkv(qbf_in, Wu, bb, BT, 3 * DIM, 0);
    } else {
      g64_qkv(qbf_in, Wu, bb, BT, DIM, 0);
      g128_qkv(kvbf_in, Wu + WSTEP, bb, BT, 2 * DIM, DIM);
    }
    fused_attn_kernel<<<dim3(T / 64, NH, B), 256, 0, stream>>>(qb, kb, vTb, aobf, causal);
    g64_f(aobf, Wu + 3 * WSTEP, bb + 3 * DIM, outbuf, BT, DIM, DIM);
  };

  auto ff = [&](const ushort* xbf, int layer, const float* b1, const float* mod,
                const float* b2, float* o) {
    const ushort* Wf = WF + (size_t)layer * 2 * FFW;
    g128_b(xbf, Wf, b1, hbf, BT, 4 * H, DIM);
    modrelu_kernel<<<dim3(BT, H / 256), 256, 0, stream>>>(hbf, mod);
    g64_f(hbf, Wf + FFW, b2, o, BT, DIM, 4 * H);
  };

  embed_rope_kernel<<<2 * BT, 256, 0, stream>>>(src, tgt, emb, xsrc, xbf_src,
                                                xtgt, xbf_tgt);

  for (int l = 0; l < LE; ++l) {
    attention(xbf_src, xbf_src, l, enc_attn_b + (size_t)l * 4 * DIM, 0, tbuf);
    resid_qnorm_kernel<<<BT, 256, 0, stream>>>(
        xsrc, tbuf, enc_norm_g + (size_t)(l * 2 + 0) * DIM,
        enc_norm_b + (size_t)(l * 2 + 0) * DIM, xbf_src);
    ff(xbf_src, l, enc_ff_b1 + (size_t)l * H * 4, enc_ff_mod + (size_t)l * H,
       enc_ff_b2 + (size_t)l * DIM, tbuf);
    resid_qnorm_kernel<<<BT, 256, 0, stream>>>(
        xsrc, tbuf, enc_norm_g + (size_t)(l * 2 + 1) * DIM,
        enc_norm_b + (size_t)(l * 2 + 1) * DIM, xbf_src);
  }

  for (int l = 0; l < LD; ++l) {
    attention(xbf_tgt, xbf_tgt, 2 + l, dec_sa_b + (size_t)l * 4 * DIM, 1, tbuf);
    resid_qnorm_kernel<<<BT, 256, 0, stream>>>(
        xtgt, tbuf, dec_norm_g + (size_t)(l * 3 + 0) * DIM,
        dec_norm_b + (size_t)(l * 3 + 0) * DIM, xbf_tgt);
    attention(xbf_tgt, xbf_src, 4 + l, dec_ca_b + (size_t)l * 4 * DIM, 0, tbuf);
    resid_qnorm_kernel<<<BT, 256, 0, stream>>>(
        xtgt, tbuf, dec_norm_g + (size_t)(l * 3 + 1) * DIM,
        dec_norm_b + (size_t)(l * 3 + 1) * DIM, xbf_tgt);
    ff(xbf_tgt, 2 + l, dec_ff_b1 + (size_t)l * H * 4, dec_ff_mod + (size_t)l * H,
       dec_ff_b2 + (size_t)l * DIM, tbuf);
    resid_qnorm_kernel<<<BT, 256, 0, stream>>>(
        xtgt, tbuf, dec_norm_g + (size_t)(l * 3 + 2) * DIM,
        dec_norm_b + (size_t)(l * 3 + 2) * DIM, xbf_tgt);
  }

  to_real_kernel<<<BT, 256, 0, stream>>>(xtgt, realbf);
  g128_f(realbf, Wfc, fc_b, out, BT, V, 256);
}